// Round 4
// baseline (413.152 us; speedup 1.0000x reference)
//
#include <hip/hip_runtime.h>
#include <hip/hip_bf16.h>
#include <hip/hip_cooperative_groups.h>

namespace cg = cooperative_groups;

constexpr int B_ = 4;
constexpr int L_ = 2048;
constexpr int D_ = 256;
constexpr int P_ = 32;
constexpr int CL = 32;   // chunk length for KV scan
constexpr int NC = L_ / CL;  // 64 chunks

#define PI_F 3.14159265358979323846f
#define INV_SQRT_P 0.17677669529663687f  // 1/sqrt(32)

typedef __attribute__((ext_vector_type(8))) short short8_t;
typedef __attribute__((ext_vector_type(4))) float floatx4;

static __device__ inline short f2bf(float f) {
  unsigned int u;
  __builtin_memcpy(&u, &f, 4);
  unsigned int r = (u + 0x7fffu + ((u >> 16) & 1u)) >> 16;
  return (short)r;
}
static __device__ inline float bf2f(short s) {
  unsigned int u = ((unsigned int)(unsigned short)s) << 16;
  float f;
  __builtin_memcpy(&f, &u, 4);
  return f;
}

// Shared-LDS union across phases. Max member = g32 (52.2 KB).
union __align__(16) SMem {
  struct { float YL[2][16][132]; float gsh[2][16]; } a3;
  struct { short As[2][32][136]; short Bs[2][64][136]; } g32;
  struct { short SPL[2][64][40]; } cd;
  struct { short SL[32][40]; short PR[32][40]; float CMB[32][260];
           float scl[32]; float mu_s[32]; float rs_s[32]; } fg;
};

// ---- GEMM phase: 32x64 tiles, two virtual 256-thread sub-blocks/block ----
// 1024 tiles over 512 virtual slots -> 2 passes. Barrier counts identical
// across sub-blocks (same KTILES, same passes).
template <int KTILES, int MODE>
__device__ __forceinline__ void phase_gemm(const short* __restrict__ A0,
                                           const short* __restrict__ A1,
                                           const short* __restrict__ W,
                                           const float* __restrict__ bias,
                                           const float* __restrict__ xres,
                                           float* __restrict__ outf,
                                           short* __restrict__ outb,
                                           SMem* sm, int bid, int tid5) {
  int sub = tid5 >> 8, tid = tid5 & 255;
  int lane = tid & 63, w = tid >> 6;
  int nw = w * 16;
  int r2 = tid >> 4, c8 = tid & 15;
  int ml = lane & 15, quad = lane >> 4, kq = quad * 8;
  const int K = KTILES * 128;
  for (int pass = 0; pass < 2; ++pass) {
    int vb = pass * 512 + bid * 2 + sub;
    int mg = vb >> 2, ng = vb & 3;
    int tok0 = mg * 32, n0 = ng * 64;
    floatx4 acc[2] = {{0.f, 0.f, 0.f, 0.f}, {0.f, 0.f, 0.f, 0.f}};
    for (int kt = 0; kt < KTILES; ++kt) {
      const short* Asrc;
      int cb;
      if (KTILES == 4) {
        Asrc = (kt < 2) ? A0 : A1;
        cb = (kt & 1) * 128;
      } else {
        Asrc = A0;
        cb = kt * 128;
      }
#pragma unroll
      for (int p2 = 0; p2 < 2; ++p2) {
        int row = p2 * 16 + r2;
        *(short8_t*)&sm->g32.As[sub][row][c8 * 8] =
            *(const short8_t*)&Asrc[(tok0 + row) * 256 + cb + c8 * 8];
      }
#pragma unroll
      for (int p2 = 0; p2 < 4; ++p2) {
        int row = p2 * 16 + r2;
        *(short8_t*)&sm->g32.Bs[sub][row][c8 * 8] =
            *(const short8_t*)&W[(n0 + row) * K + kt * 128 + c8 * 8];
      }
      __syncthreads();
#pragma unroll
      for (int s = 0; s < 4; ++s) {
        short8_t a0 = *(short8_t*)&sm->g32.As[sub][ml][s * 32 + kq];
        short8_t a1 = *(short8_t*)&sm->g32.As[sub][16 + ml][s * 32 + kq];
        short8_t b0 = *(short8_t*)&sm->g32.Bs[sub][nw + ml][s * 32 + kq];
        acc[0] = __builtin_amdgcn_mfma_f32_16x16x32_bf16(a0, b0, acc[0], 0, 0, 0);
        acc[1] = __builtin_amdgcn_mfma_f32_16x16x32_bf16(a1, b0, acc[1], 0, 0, 0);
      }
      __syncthreads();
    }
    int n = n0 + nw + ml;
    float bv = bias[n];
#pragma unroll
    for (int mt = 0; mt < 2; ++mt) {
#pragma unroll
      for (int rg = 0; rg < 4; ++rg) {
        int tok = tok0 + mt * 16 + quad * 4 + rg;
        float v = acc[mt][rg] + bv;
        if (MODE == 1) {
          float g = 0.5f * v * (1.f + erff(v * 0.70710678118654752f));
          outb[tok * 256 + n] = f2bf(g);
        } else {
          outf[tok * 256 + n] = xres[tok * 256 + n] + v;
        }
      }
    }
  }
}

__global__ __launch_bounds__(512, 2) void mega(
    const float* __restrict__ x, const float* __restrict__ pos,
    const float* __restrict__ w_val, const float* __restrict__ w_mem1v,
    const float* __restrict__ w_off, const float* __restrict__ b_off,
    const float* __restrict__ w_key, const float* __restrict__ w_gate,
    const float* __restrict__ w_sk1, const float* __restrict__ w_out,
    const float* __restrict__ w_sk2, const float* __restrict__ w_mem1o,
    const float* __restrict__ b_mem1v, const float* __restrict__ b_key,
    const float* __restrict__ b_gate, const float* __restrict__ b_val,
    const float* __restrict__ b_sk1, const float* __restrict__ b_sk2,
    const float* __restrict__ b_mem1o, const float* __restrict__ ln_g,
    const float* __restrict__ ln_b, const float* __restrict__ b_out,
    float* __restrict__ out, float* __restrict__ ws) {
  __shared__ SMem sm;
  cg::grid_group grid = cg::this_grid();
  int bid = blockIdx.x;       // 0..255
  int tid5 = threadIdx.x;     // 0..511
  int sub = tid5 >> 8, tid = tid5 & 255;

  // workspace layout (identical to host arithmetic)
  const int BLP = B_ * L_ * P_;
  const int BLD = B_ * L_ * D_;
  float* m1cT = ws;
  float* m1sT = m1cT + BLP;
  float* qc = m1sT + BLP;
  float* qs = qc + BLP;
  float* sg = qs + BLP;
  float* poff = sg + B_ * L_;
  float* ctxsum = poff + L_ * P_;
  short* UT = (short*)(ctxsum + B_ * 64 * 256);
  short* xbf = UT + (size_t)B_ * NC * 256 * 64;
  short* cbn = xbf;                   // aliases xbf (xbf dead after gemm1)
  short* ctxbf = xbf + BLD;
  short* hs = ctxbf + BLD;
  short* gvT = hs + BLD;
  short* K2bf = gvT + BLD;
  short* SPbf = K2bf + B_ * L_ * 64;
  short* WA = SPbf + B_ * L_ * 64;
  short* W1 = WA + 384 * 256;
  short* WO = W1 + 256 * 512;
  short* W2T = WO + 256 * 256;
  short* W1OT = W2T + 32 * 256;

  // =================== P0: wprep (3776 virtual blocks) ===================
  for (int p = 0; p < 8; ++p) {
    int blk = p * 512 + bid * 2 + sub;
    if (blk >= 3776) break;
    if (blk < 384) {
      int idx = blk * 256 + tid;
      int n = idx >> 8, k = idx & 255;
      float v;
      if (n < 256) v = w_val[k * 256 + n];
      else if (n < 288) v = w_mem1v[k * 32 + (n - 256)];
      else if (n < 320) v = w_off[k * 32 + (n - 288)];
      else if (n < 352) v = w_key[k * 32 + (n - 320)];
      else if (n == 352) v = w_gate[k];
      else v = 0.f;
      WA[idx] = f2bf(v);
    } else if (blk < 896) {
      int idx = (blk - 384) * 256 + tid;
      int n = idx >> 9, k = idx & 511;
      W1[idx] = f2bf(w_sk1[k * 256 + n]);
    } else if (blk < 1152) {
      int idx = (blk - 896) * 256 + tid;
      int n = idx >> 8, k = idx & 255;
      WO[idx] = f2bf(w_out[k * 256 + n]);
    } else if (blk < 1184) {
      int idx = (blk - 1152) * 256 + tid;
      int pp = idx >> 8, k = idx & 255;
      W2T[idx] = f2bf(w_sk2[k * 32 + pp]);
    } else if (blk < 1216) {
      int idx = (blk - 1184) * 256 + tid;
      int d = idx >> 5, pp = idx & 31;
      W1OT[idx] = f2bf(w_mem1o[pp * 256 + d]);
    } else if (blk < 3264) {
      int idx = ((blk - 1216) * 256 + tid) * 4;
      float4 v = *(const float4*)&x[idx];
      short4 o;
      o.x = f2bf(v.x); o.y = f2bf(v.y); o.z = f2bf(v.z); o.w = f2bf(v.w);
      *(short4*)&xbf[idx] = o;
    } else if (blk < 3520) {
      int idx = (blk - 3264) * 256 + tid;
      int l = idx >> 5, pp = idx & 31;
      float a = b_off[pp];
#pragma unroll 8
      for (int j = 0; j < 32; ++j) a += pos[l * 32 + j] * w_off[(256 + j) * 32 + pp];
      poff[idx] = a;
    } else {
      int c2 = blk - 3520;
      int b = c2 >> 6, ch = c2 & 63;
      int xb = (b * L_ + ch * 32) * 256 + tid;
      float s = 0.f;
#pragma unroll 8
      for (int i = 0; i < 32; ++i) s += x[xb + i * 256];
      ctxsum[c2 * 256 + tid] = s;
    }
  }
  grid.sync();

  // ============ P1: gemmA3 (512 virtual 16-token chunks) =================
  {
    int lane = tid & 63, w = tid >> 6;
    int ml = lane & 15, quad = lane >> 4, kq = quad * 8;
    int vb = bid * 2 + sub;
    int bc32 = vb >> 1, half = vb & 1;
    int tok0 = vb * 16;
    floatx4 acc[6] = {};
    const short* A0p = &xbf[(tok0 + ml) * 256 + kq];
    const short* Bp = &WA[(w * 96 + ml) * 256 + kq];
#pragma unroll
    for (int ks = 0; ks < 8; ++ks) {
      short8_t a0 = *(const short8_t*)(A0p + ks * 32);
#pragma unroll
      for (int nt = 0; nt < 6; ++nt) {
        short8_t b = *(const short8_t*)(Bp + nt * 16 * 256 + ks * 32);
        acc[nt] = __builtin_amdgcn_mfma_f32_16x16x32_bf16(a0, b, acc[nt], 0, 0, 0);
      }
    }
    // stage cols 256..383 into LDS (fp32)
#pragma unroll
    for (int nt = 0; nt < 6; ++nt) {
      int col = w * 96 + nt * 16 + ml;
      if (col >= 256) {
#pragma unroll
        for (int r = 0; r < 4; ++r) sm.a3.YL[sub][quad * 4 + r][col - 256] = acc[nt][r];
      }
    }
    __syncthreads();
    // A3 elementwise: 16 tok x 32 p per sub-block
#pragma unroll
    for (int it = 0; it < 2; ++it) {
      int idx = it * 256 + tid;
      int t = idx >> 5, pp = idx & 31;
      int tok = tok0 + t, l = tok & (L_ - 1);
      int b = tok >> 11;
      float v1 = sm.a3.YL[sub][t][pp] + b_mem1v[pp];
      float ph = pos[l * 32 + pp];
      float pc = cosf(ph), ps = sinf(ph);
      int idxT = (b * 32 + pp) * L_ + l;
      m1cT[idxT] = pc * v1;
      m1sT[idxT] = ps * v1;
      float off = tanhf(sm.a3.YL[sub][t][32 + pp] + poff[l * 32 + pp]) * PI_F;
      float oc = cosf(off), os = sinf(off);
      int gidx = tok * 32 + pp;
      qc[gidx] = pc * oc - ps * os;
      qs[gidx] = ps * oc + pc * os;
      float kp = tanhf(sm.a3.YL[sub][t][64 + pp] + b_key[pp]) * PI_F;
      K2bf[tok * 64 + pp] = f2bf(cosf(kp));
      K2bf[tok * 64 + 32 + pp] = f2bf(sinf(kp));
      if (pp == 0) {
        float g = 1.f / (1.f + expf(-(sm.a3.YL[sub][t][96] + b_gate[0])));
        sg[tok] = g;
        sm.a3.gsh[sub][t] = g;
      }
    }
    __syncthreads();
    // gvT = (values + b_val) * gate for cols < 256
#pragma unroll
    for (int nt = 0; nt < 6; ++nt) {
      int col = w * 96 + nt * 16 + ml;
      if (col < 256) {
        float bv = b_val[col];
        int t0 = quad * 4;
        short4 o;
        o.x = f2bf((acc[nt][0] + bv) * sm.a3.gsh[sub][t0 + 0]);
        o.y = f2bf((acc[nt][1] + bv) * sm.a3.gsh[sub][t0 + 1]);
        o.z = f2bf((acc[nt][2] + bv) * sm.a3.gsh[sub][t0 + 2]);
        o.w = f2bf((acc[nt][3] + bv) * sm.a3.gsh[sub][t0 + 3]);
        *(short4*)&gvT[(bc32 * 256 + col) * 32 + half * 16 + t0] = o;
      }
    }
  }
  grid.sync();

  // ============ P2: scans (per-wave, barrier-free) =======================
  {
    int gw = bid * 8 + (tid5 >> 6);   // 0..2047 wave tasks
    int lane = tid5 & 63;
    if (gw < 260) {
      float* arr;
      int base;
      if (gw < 128) { arr = m1cT; base = gw * L_; }
      else if (gw < 256) { arr = m1sT; base = (gw - 128) * L_; }
      else { arr = sg; base = (gw - 256) * L_; }
      float v[32];
#pragma unroll
      for (int i = 0; i < 32; ++i) v[i] = arr[base + i * 64 + lane];
      float carry = 0.f;
#pragma unroll
      for (int i = 0; i < 32; ++i) {
        float vv = v[i];
#pragma unroll
        for (int off = 1; off < 64; off <<= 1) {
          float n = __shfl_up(vv, off, 64);
          if (lane >= off) vv += n;
        }
        vv += carry;
        arr[base + i * 64 + lane] = vv;
        carry = __shfl(vv, 63, 64);
      }
    } else if (gw >= 1024) {
      // ctx: 1024 wave tasks = 256 chunks x 4 d-quarters
      int ct = gw - 1024;
      int c2 = ct >> 2, dp = ct & 3;
      int b = c2 >> 6, ch = c2 & 63;
      int d = dp * 64 + lane;
      float run = 0.f;
      int sb = b * 64 * 256 + d;
      int c = 0;
      for (; c + 8 <= ch; c += 8) {
        float t0 = ctxsum[sb + (c + 0) * 256];
        float t1 = ctxsum[sb + (c + 1) * 256];
        float t2 = ctxsum[sb + (c + 2) * 256];
        float t3 = ctxsum[sb + (c + 3) * 256];
        float t4 = ctxsum[sb + (c + 4) * 256];
        float t5 = ctxsum[sb + (c + 5) * 256];
        float t6 = ctxsum[sb + (c + 6) * 256];
        float t7 = ctxsum[sb + (c + 7) * 256];
        run += ((t0 + t1) + (t2 + t3)) + ((t4 + t5) + (t6 + t7));
      }
      for (; c < ch; ++c) run += ctxsum[sb + c * 256];
      int xb = (b * L_ + ch * 32) * 256 + d;
#pragma unroll 8
      for (int i = 0; i < 32; ++i) {
        run += x[xb + i * 256];
        int l = ch * 32 + i;
        ctxbf[xb + i * 256] = f2bf(run / (float)(l + 1));
      }
    }
  }
  grid.sync();

  // ============ P3: gemm1 -> hs ==========================================
  phase_gemm<4, 1>(xbf, ctxbf, W1, b_sk1, nullptr, nullptr, hs, &sm, bid, tid5);
  grid.sync();

  // ============ P4: CD (512 virtual blocks: chunk x d-half) ==============
  {
    int lane = tid & 63, w = tid >> 6;
    int ml = lane & 15, quad = lane >> 4, kq = quad * 8;
    int vb = bid * 2 + sub;
    int bc = vb >> 1, dh = vb & 1;
    int tok0 = bc * 32;
    int th = w & 1, ph = w >> 1;
    floatx4 pacc = {};
#pragma unroll
    for (int s = 0; s < 8; ++s) {
      short8_t a = *(const short8_t*)&hs[(tok0 + th * 16 + ml) * 256 + s * 32 + kq];
      short8_t b0 = *(const short8_t*)&W2T[(ph * 16 + ml) * 256 + s * 32 + kq];
      pacc = __builtin_amdgcn_mfma_f32_16x16x32_bf16(a, b0, pacc, 0, 0, 0);
    }
    {
      int pp = ph * 16 + ml;
      float bs = b_sk2[pp];
#pragma unroll
      for (int r = 0; r < 4; ++r) {
        int tl = th * 16 + quad * 4 + r;
        int tok = tok0 + tl;
        float sp = tanhf(pacc[r] + bs) * PI_F;
        short c = f2bf(cosf(sp)), s2 = f2bf(sinf(sp));
        sm.cd.SPL[sub][pp][tl] = c;
        sm.cd.SPL[sub][32 + pp][tl] = s2;
        if (dh == 0) {
          SPbf[tok * 64 + pp] = c;
          SPbf[tok * 64 + 32 + pp] = s2;
        }
      }
    }
    __syncthreads();
    short8_t a[4];
#pragma unroll
    for (int mt = 0; mt < 4; ++mt) a[mt] = *(short8_t*)&sm.cd.SPL[sub][mt * 16 + ml][kq];
    floatx4 acc[4][2] = {};
#pragma unroll
    for (int nt = 0; nt < 2; ++nt) {
      int d = dh * 128 + w * 32 + nt * 16 + ml;
      short8_t b = *(const short8_t*)&gvT[(bc * 256 + d) * 32 + kq];
#pragma unroll
      for (int mt = 0; mt < 4; ++mt)
        acc[mt][nt] = __builtin_amdgcn_mfma_f32_16x16x32_bf16(a[mt], b, acc[mt][nt], 0, 0, 0);
    }
#pragma unroll
    for (int mt = 0; mt < 4; ++mt)
#pragma unroll
      for (int nt = 0; nt < 2; ++nt) {
        int d = dh * 128 + w * 32 + nt * 16 + ml;
        short4 o;
        o.x = f2bf(acc[mt][nt][0]);
        o.y = f2bf(acc[mt][nt][1]);
        o.z = f2bf(acc[mt][nt][2]);
        o.w = f2bf(acc[mt][nt][3]);
        *(short4*)&UT[(bc * 256 + d) * 64 + mt * 16 + quad * 4] = o;
      }
  }
  grid.sync();

  // ============ P5: E (exclusive chunk prefix on UT) =====================
  {
    int vt = bid * 512 + tid5;
    if (vt < 65536) {
      int q = vt & 63;
      int d = (vt >> 6) & 255;
      int b = vt >> 14;
      int base = ((b * NC) * 256 + d) * 64 + q;
      const int cs = 256 * 64;
      short v[64];
#pragma unroll
      for (int c = 0; c < 64; ++c) v[c] = UT[base + c * cs];
      float run = 0.f;
#pragma unroll
      for (int c = 0; c < 64; ++c) {
        UT[base + c * cs] = f2bf(run);
        run += bf2f(v[c]);
      }
    }
  }
  grid.sync();

  // ============ P6: FG (one 512-thread block per chunk) ==================
  {
    int bc = bid;
    int lbase = bc * CL;
    int bb = bc >> 6, lloc = (bc & 63) * 32;
    if (tid5 < 32) sm.fg.scl[tid5] = rsqrtf(fmaxf(sg[lbase + tid5], 1.f)) * INV_SQRT_P;
#pragma unroll
    for (int it = 0; it < 2; ++it) {
      int i = it * 512 + tid5;
      int pp = i >> 5, t = i & 31;
      int gT = (bb * 32 + pp) * L_ + lloc + t;
      int g = (lbase + t) * 32 + pp;
      sm.fg.PR[t][pp] = f2bf((m1cT[gT] * qc[g] + m1sT[gT] * qs[g]) * INV_SQRT_P);
    }
    int lane = tid5 & 63, w = tid5 >> 6;
    int ml = lane & 15, quad = lane >> 4, kq = quad * 8;
    int d0 = w * 32;
    floatx4 acc[2][2] = {};
    short8_t ka0 = *(const short8_t*)&K2bf[(lbase + ml) * 64 + kq];
    short8_t ka1 = *(const short8_t*)&K2bf[(lbase + 16 + ml) * 64 + kq];
    short8_t kb0 = *(const short8_t*)&K2bf[(lbase + ml) * 64 + 32 + kq];
    short8_t kb1 = *(const short8_t*)&K2bf[(lbase + 16 + ml) * 64 + 32 + kq];
#pragma unroll
    for (int nt = 0; nt < 2; ++nt) {
      short8_t b = *(const short8_t*)&UT[(bc * 256 + d0 + nt * 16 + ml) * 64 + kq];
      acc[0][nt] = __builtin_amdgcn_mfma_f32_16x16x32_bf16(ka0, b, acc[0][nt], 0, 0, 0);
      acc[1][nt] = __builtin_amdgcn_mfma_f32_16x16x32_bf16(ka1, b, acc[1][nt], 0, 0, 0);
    }
    if (w == 0) {
      floatx4 sacc[2][2] = {};
#pragma unroll
      for (int ks2 = 0; ks2 < 2; ++ks2) {
        short8_t a0 = (ks2 == 0) ? ka0 : kb0;
        short8_t a1 = (ks2 == 0) ? ka1 : kb1;
        short8_t b0 = *(const short8_t*)&SPbf[(lbase + ml) * 64 + ks2 * 32 + kq];
        short8_t b1 = *(const short8_t*)&SPbf[(lbase + 16 + ml) * 64 + ks2 * 32 + kq];
        sacc[0][0] = __builtin_amdgcn_mfma_f32_16x16x32_bf16(a0, b0, sacc[0][0], 0, 0, 0);
        sacc[0][1] = __builtin_amdgcn_mfma_f32_16x16x32_bf16(a0, b1, sacc[0][1], 0, 0, 0);
        sacc[1][0] = __builtin_amdgcn_mfma_f32_16x16x32_bf16(a1, b0, sacc[1][0], 0, 0, 0);
        sacc[1][1] = __builtin_amdgcn_mfma_f32_16x16x32_bf16(a1, b1, sacc[1][1], 0, 0, 0);
      }
#pragma unroll
      for (int mt = 0; mt < 2; ++mt)
#pragma unroll
        for (int nt = 0; nt < 2; ++nt)
#pragma unroll
          for (int r = 0; r < 4; ++r) {
            int trow = mt * 16 + quad * 4 + r;
            int scol = nt * 16 + ml;
            float v = (scol <= trow) ? sacc[mt][nt][r] : 0.f;
            sm.fg.SL[trow][scol] = f2bf(v);
          }
    }
    __syncthreads();
#pragma unroll
    for (int nt = 0; nt < 2; ++nt) {
      short8_t b = *(const short8_t*)&UT[(bc * 256 + d0 + nt * 16 + ml) * 64 + 32 + kq];
      acc[0][nt] = __builtin_amdgcn_mfma_f32_16x16x32_bf16(kb0, b, acc[0][nt], 0, 0, 0);
      acc[1][nt] = __builtin_amdgcn_mfma_f32_16x16x32_bf16(kb1, b, acc[1][nt], 0, 0, 0);
    }
    {
      short8_t a0 = *(short8_t*)&sm.fg.SL[ml][kq];
      short8_t a1 = *(short8_t*)&sm.fg.SL[16 + ml][kq];
#pragma unroll
      for (int nt = 0; nt < 2; ++nt) {
        short8_t b = *(const short8_t*)&gvT[(bc * 256 + d0 + nt * 16 + ml) * 32 + kq];
        acc[0][nt] = __builtin_amdgcn_mfma_f32_16x16x32_bf16(a0, b, acc[0][nt], 0, 0, 0);
        acc[1][nt] = __builtin_amdgcn_mfma_f32_16x16x32_bf16(a1, b, acc[1][nt], 0, 0, 0);
      }
    }
    floatx4 macc[2][2] = {};
    {
      short8_t a0 = *(short8_t*)&sm.fg.PR[ml][kq];
      short8_t a1 = *(short8_t*)&sm.fg.PR[16 + ml][kq];
#pragma unroll
      for (int nt = 0; nt < 2; ++nt) {
        short8_t b = *(const short8_t*)&W1OT[(d0 + nt * 16 + ml) * 32 + kq];
        macc[0][nt] = __builtin_amdgcn_mfma_f32_16x16x32_bf16(a0, b, macc[0][nt], 0, 0, 0);
        macc[1][nt] = __builtin_amdgcn_mfma_f32_16x16x32_bf16(a1, b, macc[1][nt], 0, 0, 0);
      }
    }
#pragma unroll
    for (int mt = 0; mt < 2; ++mt)
#pragma unroll
      for (int nt = 0; nt < 2; ++nt) {
        int d = d0 + nt * 16 + ml;
        float bm = b_mem1o[d];
#pragma unroll
        for (int r = 0; r < 4; ++r) {
          int t = mt * 16 + quad * 4 + r;
          sm.fg.CMB[t][d] = acc[mt][nt][r] * sm.fg.scl[t] + macc[mt][nt][r] + bm;
        }
      }
    __syncthreads();
    {
      int t = tid5 >> 4, g = tid5 & 15;
      float s = 0.f, s2 = 0.f;
#pragma unroll
      for (int j = 0; j < 16; ++j) {
        float v = sm.fg.CMB[t][g + j * 16];
        s += v;
        s2 += v * v;
      }
#pragma unroll
      for (int m = 1; m < 16; m <<= 1) {
        s += __shfl_xor(s, m, 64);
        s2 += __shfl_xor(s2, m, 64);
      }
      if (g == 0) {
        float mu = s / (float)D_;
        float var = s2 / (float)D_ - mu * mu;
        sm.fg.mu_s[t] = mu;
        sm.fg.rs_s[t] = rsqrtf(var + 1e-5f);
      }
    }
    __syncthreads();
    {
      int d = tid5 & 255, th = tid5 >> 8;
      float lg = ln_g[d], lb = ln_b[d];
#pragma unroll
      for (int i = 0; i < 16; ++i) {
        int t = th * 16 + i;
        cbn[(lbase + t) * 256 + d] = f2bf((sm.fg.CMB[t][d] - sm.fg.mu_s[t]) * sm.fg.rs_s[t] * lg + lb);
      }
    }
  }
  grid.sync();

  // ============ P7: gemm2 -> out =========================================
  phase_gemm<2, 2>(cbn, nullptr, WO, b_out, x, out, nullptr, &sm, bid, tid5);
}

extern "C" void kernel_launch(void* const* d_in, const int* in_sizes, int n_in,
                              void* d_out, int out_size, void* d_ws, size_t ws_size,
                              hipStream_t stream) {
  const float* x = (const float*)d_in[0];
  const float* pos = (const float*)d_in[1];
  const float* w_mem1v = (const float*)d_in[2];
  const float* b_mem1v = (const float*)d_in[3];
  const float* w_mem1o = (const float*)d_in[4];
  const float* b_mem1o = (const float*)d_in[5];
  const float* w_off = (const float*)d_in[6];
  const float* b_off = (const float*)d_in[7];
  const float* w_key = (const float*)d_in[8];
  const float* b_key = (const float*)d_in[9];
  const float* w_val = (const float*)d_in[10];
  const float* b_val = (const float*)d_in[11];
  const float* w_sk1 = (const float*)d_in[12];
  const float* b_sk1 = (const float*)d_in[13];
  const float* w_sk2 = (const float*)d_in[14];
  const float* b_sk2 = (const float*)d_in[15];
  const float* w_gate = (const float*)d_in[16];
  const float* b_gate = (const float*)d_in[17];
  const float* ln_g = (const float*)d_in[18];
  const float* ln_b = (const float*)d_in[19];
  const float* w_out = (const float*)d_in[20];
  const float* b_out = (const float*)d_in[21];
  float* out = (float*)d_out;
  float* ws = (float*)d_ws;

  void* args[] = {
      (void*)&x, (void*)&pos, (void*)&w_val, (void*)&w_mem1v,
      (void*)&w_off, (void*)&b_off, (void*)&w_key, (void*)&w_gate,
      (void*)&w_sk1, (void*)&w_out, (void*)&w_sk2, (void*)&w_mem1o,
      (void*)&b_mem1v, (void*)&b_key, (void*)&b_gate, (void*)&b_val,
      (void*)&b_sk1, (void*)&b_sk2, (void*)&b_mem1o, (void*)&ln_g,
      (void*)&ln_b, (void*)&b_out, (void*)&out, (void*)&ws};
  hipLaunchCooperativeKernel((const void*)mega, dim3(256), dim3(512), args, 0, stream);
}

// Round 5
// 172.271 us; speedup vs baseline: 2.3983x; 2.3983x over previous
//
#include <hip/hip_runtime.h>
#include <hip/hip_bf16.h>

constexpr int B_ = 4;
constexpr int L_ = 2048;
constexpr int D_ = 256;
constexpr int P_ = 32;
constexpr int CL = 32;   // chunk length for KV scan
constexpr int NC = L_ / CL;  // 64 chunks

#define PI_F 3.14159265358979323846f
#define INV_SQRT_P 0.17677669529663687f  // 1/sqrt(32)

typedef __attribute__((ext_vector_type(8))) short short8_t;
typedef __attribute__((ext_vector_type(4))) float floatx4;

static __device__ inline short f2bf(float f) {
  unsigned int u;
  __builtin_memcpy(&u, &f, 4);
  unsigned int r = (u + 0x7fffu + ((u >> 16) & 1u)) >> 16;
  return (short)r;
}
static __device__ inline float bf2f(short s) {
  unsigned int u = ((unsigned int)(unsigned short)s) << 16;
  float f;
  __builtin_memcpy(&f, &u, 4);
  return f;
}

// ---------------- wprep: weight casts/transposes + x->bf16 + poff + ctxsum -
__global__ void wprep(const float* __restrict__ x, const float* __restrict__ pos,
                      const float* __restrict__ w_val, const float* __restrict__ w_mem1v,
                      const float* __restrict__ w_off, const float* __restrict__ b_off,
                      const float* __restrict__ w_key, const float* __restrict__ w_gate,
                      const float* __restrict__ w_sk1, const float* __restrict__ w_out,
                      const float* __restrict__ w_sk2, const float* __restrict__ w_mem1o,
                      short* __restrict__ WA, short* __restrict__ W1,
                      short* __restrict__ WO, short* __restrict__ W2T,
                      short* __restrict__ W1OT,
                      short* __restrict__ xbf, float* __restrict__ poff,
                      float* __restrict__ ctxsum) {
  int blk = blockIdx.x, tid = threadIdx.x;
  if (blk < 384) {
    int idx = blk * 256 + tid;
    int n = idx >> 8, k = idx & 255;
    float v;
    if (n < 256) v = w_val[k * 256 + n];
    else if (n < 288) v = w_mem1v[k * 32 + (n - 256)];
    else if (n < 320) v = w_off[k * 32 + (n - 288)];
    else if (n < 352) v = w_key[k * 32 + (n - 320)];
    else if (n == 352) v = w_gate[k];
    else v = 0.f;
    WA[idx] = f2bf(v);
  } else if (blk < 896) {
    int idx = (blk - 384) * 256 + tid;
    int n = idx >> 9, k = idx & 511;
    W1[idx] = f2bf(w_sk1[k * 256 + n]);
  } else if (blk < 1152) {
    int idx = (blk - 896) * 256 + tid;
    int n = idx >> 8, k = idx & 255;
    WO[idx] = f2bf(w_out[k * 256 + n]);
  } else if (blk < 1184) {
    int idx = (blk - 1152) * 256 + tid;  // p*256 + k
    int p = idx >> 8, k = idx & 255;
    W2T[idx] = f2bf(w_sk2[k * 32 + p]);
  } else if (blk < 1216) {
    int idx = (blk - 1184) * 256 + tid;  // d*32 + p
    int d = idx >> 5, p = idx & 31;
    W1OT[idx] = f2bf(w_mem1o[p * 256 + d]);
  } else if (blk < 3264) {
    int idx = ((blk - 1216) * 256 + tid) * 4;
    float4 v = *(const float4*)&x[idx];
    short4 o;
    o.x = f2bf(v.x); o.y = f2bf(v.y); o.z = f2bf(v.z); o.w = f2bf(v.w);
    *(short4*)&xbf[idx] = o;
  } else if (blk < 3520) {
    int idx = (blk - 3264) * 256 + tid;
    int l = idx >> 5, p = idx & 31;
    float a = b_off[p];
#pragma unroll 8
    for (int j = 0; j < 32; ++j) a += pos[l * 32 + j] * w_off[(256 + j) * 32 + p];
    poff[idx] = a;
  } else {
    // ctx chunk sums: depends only on x
    int c2 = blk - 3520;
    int b = c2 >> 6, ch = c2 & 63;
    int xb = (b * L_ + ch * 32) * 256 + tid;
    float s = 0.f;
#pragma unroll 8
    for (int i = 0; i < 32; ++i) s += x[xb + i * 256];
    ctxsum[c2 * 256 + tid] = s;
  }
}

// ---------------- gemmA3: fused gemm1 (Y = xbf@WA) + kernelA3 epilogue -----
// 512 blocks x 16-token chunks (384 threads, 6 waves) -> 3 waves/SIMD.
__global__ __launch_bounds__(384, 3) void gemmA3(const short* __restrict__ xbf,
                                                 const short* __restrict__ WA,
                                                 const float* __restrict__ pos,
                                                 const float* __restrict__ poff,
                                                 const float* __restrict__ b_mem1v,
                                                 const float* __restrict__ b_key,
                                                 const float* __restrict__ b_gate,
                                                 const float* __restrict__ b_val,
                                                 float* __restrict__ m1cT,
                                                 float* __restrict__ m1sT,
                                                 float* __restrict__ qc,
                                                 float* __restrict__ qs,
                                                 short* __restrict__ K2bf,
                                                 short* __restrict__ gvT,
                                                 float* __restrict__ sg) {
  __shared__ float YL[16][132];  // cols 256..383 of Y, fp32
  __shared__ float gsh[16];
  int tid = threadIdx.x;
  int lane = tid & 63, w = tid >> 6;
  int ml = lane & 15, quad = lane >> 4, kq = quad * 8;
  int bc = blockIdx.x;           // 16-token chunk
  int bc32 = bc >> 1, half = bc & 1;
  int tok0 = bc * 16;
  floatx4 acc[4] = {};
  const short* A0p = &xbf[(tok0 + ml) * 256 + kq];
  const short* Bp = &WA[(w * 64 + ml) * 256 + kq];
#pragma unroll
  for (int ks = 0; ks < 8; ++ks) {
    short8_t a0 = *(const short8_t*)(A0p + ks * 32);
#pragma unroll
    for (int nt = 0; nt < 4; ++nt) {
      short8_t b = *(const short8_t*)(Bp + nt * 16 * 256 + ks * 32);
      acc[nt] = __builtin_amdgcn_mfma_f32_16x16x32_bf16(a0, b, acc[nt], 0, 0, 0);
    }
  }
  // waves 4,5 stage cols 256..383 into LDS (fp32, no bf16 round-trip)
  if (w >= 4) {
#pragma unroll
    for (int nt = 0; nt < 4; ++nt) {
      int col = (w - 4) * 64 + nt * 16 + ml;
#pragma unroll
      for (int r = 0; r < 4; ++r)
        YL[quad * 4 + r][col] = acc[nt][r];
    }
  }
  __syncthreads();
  // A3 elementwise phase: 16 tok x 32 p = 512 items on threads 0..255
  if (tid < 256) {
#pragma unroll
    for (int it = 0; it < 2; ++it) {
      int idx = it * 256 + tid;
      int t = idx >> 5, p = idx & 31;
      int tok = tok0 + t, l = tok & (L_ - 1);
      int b = tok >> 11;
      float v1 = YL[t][p] + b_mem1v[p];
      float ph = pos[l * 32 + p];
      float pc = cosf(ph), ps = sinf(ph);
      int idxT = (b * 32 + p) * L_ + l;
      m1cT[idxT] = pc * v1;
      m1sT[idxT] = ps * v1;
      float off = tanhf(YL[t][32 + p] + poff[l * 32 + p]) * PI_F;
      float oc = cosf(off), os = sinf(off);
      int gidx = tok * 32 + p;
      qc[gidx] = pc * oc - ps * os;
      qs[gidx] = ps * oc + pc * os;
      float kp = tanhf(YL[t][64 + p] + b_key[p]) * PI_F;
      K2bf[tok * 64 + p] = f2bf(cosf(kp));
      K2bf[tok * 64 + 32 + p] = f2bf(sinf(kp));
      if (p == 0) {
        float g = 1.f / (1.f + expf(-(YL[t][96] + b_gate[0])));
        sg[tok] = g;
        gsh[t] = g;
      }
    }
  }
  __syncthreads();
  // gvT = (values + b_val) * gate, [bc32][d][t32] with t-slot = half*16+t
  if (w < 4) {
#pragma unroll
    for (int nt = 0; nt < 4; ++nt) {
      int d = w * 64 + nt * 16 + ml;
      float bv = b_val[d];
      int t0 = quad * 4;
      short4 o;
      o.x = f2bf((acc[nt][0] + bv) * gsh[t0 + 0]);
      o.y = f2bf((acc[nt][1] + bv) * gsh[t0 + 1]);
      o.z = f2bf((acc[nt][2] + bv) * gsh[t0 + 2]);
      o.w = f2bf((acc[nt][3] + bv) * gsh[t0 + 3]);
      *(short4*)&gvT[(bc32 * 256 + d) * 32 + half * 16 + t0] = o;
    }
  }
}

// ---------------- scan_all: m1 scans + sg scan + ctx prefix ----------------
__global__ void scan_all(float* __restrict__ m1cT, float* __restrict__ m1sT,
                         float* __restrict__ sg, const float* __restrict__ x,
                         const float* __restrict__ ctxsum, short* __restrict__ ctxbf) {
  int blk = blockIdx.x;
  int tid = threadIdx.x;
  if (blk >= 260) {
    // ctx: chunk prefix of ctxsum (unroll-8 batched loads) + local scan
    int c2 = blk - 260;
    int b = c2 >> 6, ch = c2 & 63;
    float run = 0.f;
    int sb = b * 64 * 256 + tid;
    int c = 0;
    for (; c + 8 <= ch; c += 8) {
      float t0 = ctxsum[sb + (c + 0) * 256];
      float t1 = ctxsum[sb + (c + 1) * 256];
      float t2 = ctxsum[sb + (c + 2) * 256];
      float t3 = ctxsum[sb + (c + 3) * 256];
      float t4 = ctxsum[sb + (c + 4) * 256];
      float t5 = ctxsum[sb + (c + 5) * 256];
      float t6 = ctxsum[sb + (c + 6) * 256];
      float t7 = ctxsum[sb + (c + 7) * 256];
      run += ((t0 + t1) + (t2 + t3)) + ((t4 + t5) + (t6 + t7));
    }
    for (; c < ch; ++c) run += ctxsum[sb + c * 256];
    int xb = (b * L_ + ch * 32) * 256 + tid;
#pragma unroll 8
    for (int i = 0; i < 32; ++i) {
      run += x[xb + i * 256];
      int l = ch * 32 + i;
      ctxbf[xb + i * 256] = f2bf(run / (float)(l + 1));
    }
    return;
  }
  int lane = tid & 63, wid = tid >> 6;
  __shared__ float wsum[4];
  float carry = 0.f;
  float* arr;
  int base;
  if (blk < 256) {
    arr = (blk < 128) ? m1cT : m1sT;
    base = (blk & 127) * L_;
  } else {
    arr = sg;
    base = (blk - 256) * L_;
  }
  float v[8];
#pragma unroll
  for (int i = 0; i < 8; ++i) v[i] = arr[base + i * 256 + tid];
#pragma unroll
  for (int i = 0; i < 8; ++i) {
    float vv = v[i];
#pragma unroll
    for (int off = 1; off < 64; off <<= 1) {
      float n = __shfl_up(vv, off, 64);
      if (lane >= off) vv += n;
    }
    if (lane == 63) wsum[wid] = vv;
    __syncthreads();
    float add = carry;
    for (int w = 0; w < wid; ++w) add += wsum[w];
    arr[base + i * 256 + tid] = vv + add;
    carry += wsum[0] + wsum[1] + wsum[2] + wsum[3];
    __syncthreads();
  }
}

// ---------------- gemmCD: fused gemm1 (hs in LDS) + kernelCD ---------------
// One block per 32-token chunk, 512 threads / 8 waves. hs never touches HBM.
union __align__(16) CDMem {
  short As[32][520];                           // A tile [xbf|ctxbf], K=512
  struct { short HS[32][280]; short SPL[64][40]; } h;
};
__global__ __launch_bounds__(512, 4) void gemmCD(const short* __restrict__ xbf,
                                                 const short* __restrict__ ctxbf,
                                                 const short* __restrict__ W1,
                                                 const float* __restrict__ b_sk1,
                                                 const short* __restrict__ W2T,
                                                 const float* __restrict__ b_sk2,
                                                 const short* __restrict__ gvT,
                                                 short* __restrict__ SPbf,
                                                 short* __restrict__ UT) {
  __shared__ CDMem sm;
  int tid = threadIdx.x;
  int bc = blockIdx.x;
  int tok0 = bc * 32;
  int lane = tid & 63, w = tid >> 6;
  int ml = lane & 15, quad = lane >> 4, kq = quad * 8;
  // stage A = [xbf | ctxbf] rows tok0..tok0+32, K=512
#pragma unroll
  for (int pass = 0; pass < 4; ++pass) {
    int idx = pass * 512 + tid;
    int row = idx >> 6, c8 = idx & 63;
    int col = c8 * 8;
    const short* src = (col < 256) ? &xbf[(tok0 + row) * 256 + col]
                                   : &ctxbf[(tok0 + row) * 256 + col - 256];
    *(short8_t*)&sm.As[row][col] = *(const short8_t*)src;
  }
  __syncthreads();
  // hs = gelu(A @ W1 + b_sk1); wave w owns n-cols [w*32, w*32+32)
  int n0w = w * 32;
  floatx4 acc[2][2] = {};
#pragma unroll
  for (int kt = 0; kt < 16; ++kt) {
    short8_t a0 = *(short8_t*)&sm.As[ml][kt * 32 + kq];
    short8_t a1 = *(short8_t*)&sm.As[16 + ml][kt * 32 + kq];
    short8_t b0 = *(const short8_t*)&W1[(n0w + ml) * 512 + kt * 32 + kq];
    short8_t b1 = *(const short8_t*)&W1[(n0w + 16 + ml) * 512 + kt * 32 + kq];
    acc[0][0] = __builtin_amdgcn_mfma_f32_16x16x32_bf16(a0, b0, acc[0][0], 0, 0, 0);
    acc[0][1] = __builtin_amdgcn_mfma_f32_16x16x32_bf16(a0, b1, acc[0][1], 0, 0, 0);
    acc[1][0] = __builtin_amdgcn_mfma_f32_16x16x32_bf16(a1, b0, acc[1][0], 0, 0, 0);
    acc[1][1] = __builtin_amdgcn_mfma_f32_16x16x32_bf16(a1, b1, acc[1][1], 0, 0, 0);
  }
  short hv[2][2][4];
#pragma unroll
  for (int nt = 0; nt < 2; ++nt) {
    float bv = b_sk1[n0w + nt * 16 + ml];
#pragma unroll
    for (int mt = 0; mt < 2; ++mt)
#pragma unroll
      for (int r = 0; r < 4; ++r) {
        float v = acc[mt][nt][r] + bv;
        float g = 0.5f * v * (1.f + erff(v * 0.70710678118654752f));
        hv[mt][nt][r] = f2bf(g);
      }
  }
  __syncthreads();  // As dead; HS aliases it
#pragma unroll
  for (int mt = 0; mt < 2; ++mt)
#pragma unroll
    for (int nt = 0; nt < 2; ++nt)
#pragma unroll
      for (int r = 0; r < 4; ++r)
        sm.h.HS[mt * 16 + quad * 4 + r][n0w + nt * 16 + ml] = hv[mt][nt][r];
  __syncthreads();
  // Phase B (waves 0..3): SP = tanh(hs @ W2T + b_sk2)*pi -> SPL + SPbf
  if (w < 4) {
    int th = w & 1, ph = w >> 1;
    floatx4 pacc = {};
#pragma unroll
    for (int s = 0; s < 8; ++s) {
      short8_t a = *(short8_t*)&sm.h.HS[th * 16 + ml][s * 32 + kq];
      short8_t b0 = *(const short8_t*)&W2T[(ph * 16 + ml) * 256 + s * 32 + kq];
      pacc = __builtin_amdgcn_mfma_f32_16x16x32_bf16(a, b0, pacc, 0, 0, 0);
    }
    int p = ph * 16 + ml;
    float bs = b_sk2[p];
#pragma unroll
    for (int r = 0; r < 4; ++r) {
      int tl = th * 16 + quad * 4 + r;
      int tok = tok0 + tl;
      float sp = tanhf(pacc[r] + bs) * PI_F;
      short c = f2bf(cosf(sp)), s2 = f2bf(sinf(sp));
      sm.h.SPL[p][tl] = c;
      sm.h.SPL[32 + p][tl] = s2;
      SPbf[tok * 64 + p] = c;
      SPbf[tok * 64 + 32 + p] = s2;
    }
  }
  __syncthreads();
  // Phase C: U chunk sums; wave w owns d in [w*32, w*32+32)
  short8_t a[4];
#pragma unroll
  for (int mt = 0; mt < 4; ++mt) a[mt] = *(short8_t*)&sm.h.SPL[mt * 16 + ml][kq];
  floatx4 acc3[4][2] = {};
#pragma unroll
  for (int nt = 0; nt < 2; ++nt) {
    int d = w * 32 + nt * 16 + ml;
    short8_t b = *(const short8_t*)&gvT[(bc * 256 + d) * 32 + kq];
#pragma unroll
    for (int mt = 0; mt < 4; ++mt)
      acc3[mt][nt] = __builtin_amdgcn_mfma_f32_16x16x32_bf16(a[mt], b, acc3[mt][nt], 0, 0, 0);
  }
#pragma unroll
  for (int mt = 0; mt < 4; ++mt)
#pragma unroll
    for (int nt = 0; nt < 2; ++nt) {
      int d = w * 32 + nt * 16 + ml;
      short4 o;
      o.x = f2bf(acc3[mt][nt][0]);
      o.y = f2bf(acc3[mt][nt][1]);
      o.z = f2bf(acc3[mt][nt][2]);
      o.w = f2bf(acc3[mt][nt][3]);
      *(short4*)&UT[(bc * 256 + d) * 64 + mt * 16 + quad * 4] = o;
    }
}

// ---------------- Kernel E: exclusive chunk prefix, pair-split (2x TLP) ----
// Lanes (2i,2i+1) share one (b,d,q): even lane scans chunks 0-31, odd 32-63.
__global__ void kernelE(short* __restrict__ UT) {
  int t = blockIdx.x * 256 + threadIdx.x;  // 131072 threads
  int pi = t >> 1, half = t & 1;
  int q = pi & 63;
  int d = (pi >> 6) & 255;
  int b = pi >> 14;
  const int cs = 256 * 64;
  int base = ((b * NC) * 256 + d) * 64 + q + half * 32 * cs;
  short v[32];
#pragma unroll
  for (int c = 0; c < 32; ++c) v[c] = UT[base + c * cs];
  float tot = 0.f;
#pragma unroll
  for (int c = 0; c < 32; ++c) tot += bf2f(v[c]);
  float other = __shfl_xor(tot, 1, 64);
  float run = half ? other : 0.f;
#pragma unroll
  for (int c = 0; c < 32; ++c) {
    UT[base + c * cs] = f2bf(run);
    run += bf2f(v[c]);
  }
}

// ---------------- fgOut: retrieval + pos_out + LN + gemm2 -> out -----------
// LN output tile stays in LDS (CBN) and feeds gemm2 directly; cbn never
// touches HBM. 256 blocks x 512 threads; wave w: FG d-cols / gemm2 n-cols.
struct __align__(16) FGMem {
  short SL[32][40];
  short PR[32][40];
  float CMB[32][260];
  short CBN[32][280];
  float LG[256], LB[256];
  float scl[32], mu_s[32], rs_s[32];
};
__global__ __launch_bounds__(512, 4) void fgOut(const short* __restrict__ UT,
                                                const short* __restrict__ SPbf,
                                                const short* __restrict__ K2bf,
                                                const short* __restrict__ gvT,
                                                const float* __restrict__ sgc,
                                                const float* __restrict__ m1cT,
                                                const float* __restrict__ m1sT,
                                                const float* __restrict__ qc,
                                                const float* __restrict__ qs,
                                                const short* __restrict__ W1OT,
                                                const float* __restrict__ b_mem1o,
                                                const float* __restrict__ ln_g,
                                                const float* __restrict__ ln_b,
                                                const short* __restrict__ WO,
                                                const float* __restrict__ b_out,
                                                const float* __restrict__ x,
                                                float* __restrict__ out) {
  __shared__ FGMem sm;
  int tid5 = threadIdx.x;
  int bc = blockIdx.x;
  int lbase = bc * CL;
  int bb = bc >> 6, lloc = (bc & 63) * 32;
  if (tid5 < 32) sm.scl[tid5] = rsqrtf(fmaxf(sgc[lbase + tid5], 1.f)) * INV_SQRT_P;
  if (tid5 >= 256 && tid5 < 512) {
    int d = tid5 - 256;
    sm.LG[d] = ln_g[d];
    sm.LB[d] = ln_b[d];
  }
#pragma unroll
  for (int it = 0; it < 2; ++it) {
    int i = it * 512 + tid5;
    int pp = i >> 5, t = i & 31;
    int gT = (bb * 32 + pp) * L_ + lloc + t;
    int g = (lbase + t) * 32 + pp;
    sm.PR[t][pp] = f2bf((m1cT[gT] * qc[g] + m1sT[gT] * qs[g]) * INV_SQRT_P);
  }
  int lane = tid5 & 63, w = tid5 >> 6;
  int ml = lane & 15, quad = lane >> 4, kq = quad * 8;
  int d0 = w * 32;
  floatx4 acc[2][2] = {};
  short8_t ka0 = *(const short8_t*)&K2bf[(lbase + ml) * 64 + kq];
  short8_t ka1 = *(const short8_t*)&K2bf[(lbase + 16 + ml) * 64 + kq];
  short8_t kb0 = *(const short8_t*)&K2bf[(lbase + ml) * 64 + 32 + kq];
  short8_t kb1 = *(const short8_t*)&K2bf[(lbase + 16 + ml) * 64 + 32 + kq];
  // Part 1, ks=0
#pragma unroll
  for (int nt = 0; nt < 2; ++nt) {
    short8_t b = *(const short8_t*)&UT[(bc * 256 + d0 + nt * 16 + ml) * 64 + kq];
    acc[0][nt] = __builtin_amdgcn_mfma_f32_16x16x32_bf16(ka0, b, acc[0][nt], 0, 0, 0);
    acc[1][nt] = __builtin_amdgcn_mfma_f32_16x16x32_bf16(ka1, b, acc[1][nt], 0, 0, 0);
  }
  if (w == 0) {
    floatx4 sacc[2][2] = {};
#pragma unroll
    for (int ks2 = 0; ks2 < 2; ++ks2) {
      short8_t a0 = (ks2 == 0) ? ka0 : kb0;
      short8_t a1 = (ks2 == 0) ? ka1 : kb1;
      short8_t b0 = *(const short8_t*)&SPbf[(lbase + ml) * 64 + ks2 * 32 + kq];
      short8_t b1 = *(const short8_t*)&SPbf[(lbase + 16 + ml) * 64 + ks2 * 32 + kq];
      sacc[0][0] = __builtin_amdgcn_mfma_f32_16x16x32_bf16(a0, b0, sacc[0][0], 0, 0, 0);
      sacc[0][1] = __builtin_amdgcn_mfma_f32_16x16x32_bf16(a0, b1, sacc[0][1], 0, 0, 0);
      sacc[1][0] = __builtin_amdgcn_mfma_f32_16x16x32_bf16(a1, b0, sacc[1][0], 0, 0, 0);
      sacc[1][1] = __builtin_amdgcn_mfma_f32_16x16x32_bf16(a1, b1, sacc[1][1], 0, 0, 0);
    }
#pragma unroll
    for (int mt = 0; mt < 2; ++mt)
#pragma unroll
      for (int nt = 0; nt < 2; ++nt)
#pragma unroll
        for (int r = 0; r < 4; ++r) {
          int trow = mt * 16 + quad * 4 + r;
          int scol = nt * 16 + ml;
          float v = (scol <= trow) ? sacc[mt][nt][r] : 0.f;
          sm.SL[trow][scol] = f2bf(v);
        }
  }
  __syncthreads();
  // Part 1, ks=1
#pragma unroll
  for (int nt = 0; nt < 2; ++nt) {
    short8_t b = *(const short8_t*)&UT[(bc * 256 + d0 + nt * 16 + ml) * 64 + 32 + kq];
    acc[0][nt] = __builtin_amdgcn_mfma_f32_16x16x32_bf16(kb0, b, acc[0][nt], 0, 0, 0);
    acc[1][nt] = __builtin_amdgcn_mfma_f32_16x16x32_bf16(kb1, b, acc[1][nt], 0, 0, 0);
  }
  // Part 2: S @ gv
  {
    short8_t a0 = *(short8_t*)&sm.SL[ml][kq];
    short8_t a1 = *(short8_t*)&sm.SL[16 + ml][kq];
#pragma unroll
    for (int nt = 0; nt < 2; ++nt) {
      short8_t b = *(const short8_t*)&gvT[(bc * 256 + d0 + nt * 16 + ml) * 32 + kq];
      acc[0][nt] = __builtin_amdgcn_mfma_f32_16x16x32_bf16(a0, b, acc[0][nt], 0, 0, 0);
      acc[1][nt] = __builtin_amdgcn_mfma_f32_16x16x32_bf16(a1, b, acc[1][nt], 0, 0, 0);
    }
  }
  // pos_out MFMA
  floatx4 macc[2][2] = {};
  {
    short8_t a0 = *(short8_t*)&sm.PR[ml][kq];
    short8_t a1 = *(short8_t*)&sm.PR[16 + ml][kq];
#pragma unroll
    for (int nt = 0; nt < 2; ++nt) {
      short8_t b = *(const short8_t*)&W1OT[(d0 + nt * 16 + ml) * 32 + kq];
      macc[0][nt] = __builtin_amdgcn_mfma_f32_16x16x32_bf16(a0, b, macc[0][nt], 0, 0, 0);
      macc[1][nt] = __builtin_amdgcn_mfma_f32_16x16x32_bf16(a1, b, macc[1][nt], 0, 0, 0);
    }
  }
#pragma unroll
  for (int mt = 0; mt < 2; ++mt)
#pragma unroll
    for (int nt = 0; nt < 2; ++nt) {
      int d = d0 + nt * 16 + ml;
      float bm = b_mem1o[d];
#pragma unroll
      for (int r = 0; r < 4; ++r) {
        int t = mt * 16 + quad * 4 + r;
        sm.CMB[t][d] = acc[mt][nt][r] * sm.scl[t] + macc[mt][nt][r] + bm;
      }
    }
  __syncthreads();
  // LN stats
  {
    int t = tid5 >> 4, g = tid5 & 15;
    float s = 0.f, s2 = 0.f;
#pragma unroll
    for (int j = 0; j < 16; ++j) {
      float v = sm.CMB[t][g + j * 16];
      s += v;
      s2 += v * v;
    }
#pragma unroll
    for (int m = 1; m < 16; m <<= 1) {
      s += __shfl_xor(s, m, 64);
      s2 += __shfl_xor(s2, m, 64);
    }
    if (g == 0) {
      float mu = s / (float)D_;
      float var = s2 / (float)D_ - mu * mu;
      sm.mu_s[t] = mu;
      sm.rs_s[t] = rsqrtf(var + 1e-5f);
    }
  }
  __syncthreads();
  // normalize -> CBN (bf16) in LDS
#pragma unroll
  for (int it = 0; it < 16; ++it) {
    int i = it * 512 + tid5;
    int t = i >> 8, d = i & 255;
    sm.CBN[t][d] = f2bf((sm.CMB[t][d] - sm.mu_s[t]) * sm.rs_s[t] * sm.LG[d] + sm.LB[d]);
  }
  __syncthreads();
  // gemm2: out = x + CBN @ WO + b_out; wave w owns n-cols [w*32, +32)
  floatx4 acc2[2][2] = {};
#pragma unroll
  for (int kt = 0; kt < 8; ++kt) {
    short8_t a0 = *(short8_t*)&sm.CBN[ml][kt * 32 + kq];
    short8_t a1 = *(short8_t*)&sm.CBN[16 + ml][kt * 32 + kq];
#pragma unroll
    for (int nt = 0; nt < 2; ++nt) {
      short8_t b = *(const short8_t*)&WO[(d0 + nt * 16 + ml) * 256 + kt * 32 + kq];
      acc2[0][nt] = __builtin_amdgcn_mfma_f32_16x16x32_bf16(a0, b, acc2[0][nt], 0, 0, 0);
      acc2[1][nt] = __builtin_amdgcn_mfma_f32_16x16x32_bf16(a1, b, acc2[1][nt], 0, 0, 0);
    }
  }
#pragma unroll
  for (int nt = 0; nt < 2; ++nt) {
    int n = d0 + nt * 16 + ml;
    float bv = b_out[n];
#pragma unroll
    for (int mt = 0; mt < 2; ++mt)
#pragma unroll
      for (int r = 0; r < 4; ++r) {
        int tok = lbase + mt * 16 + quad * 4 + r;
        out[tok * 256 + n] = x[tok * 256 + n] + acc2[mt][nt][r] + bv;
      }
  }
}

extern "C" void kernel_launch(void* const* d_in, const int* in_sizes, int n_in,
                              void* d_out, int out_size, void* d_ws, size_t ws_size,
                              hipStream_t stream) {
  const float* x = (const float*)d_in[0];
  const float* pos = (const float*)d_in[1];
  const float* w_mem1v = (const float*)d_in[2];
  const float* b_mem1v = (const float*)d_in[3];
  const float* w_mem1o = (const float*)d_in[4];
  const float* b_mem1o = (const float*)d_in[5];
  const float* w_off = (const float*)d_in[6];
  const float* b_off = (const float*)d_in[7];
  const float* w_key = (const float*)d_in[8];
  const float* b_key = (const float*)d_in[9];
  const float* w_val = (const float*)d_in[10];
  const float* b_val = (const float*)d_in[11];
  const float* w_sk1 = (const float*)d_in[12];
  const float* b_sk1 = (const float*)d_in[13];
  const float* w_sk2 = (const float*)d_in[14];
  const float* b_sk2 = (const float*)d_in[15];
  const float* w_gate = (const float*)d_in[16];
  const float* b_gate = (const float*)d_in[17];
  const float* ln_g = (const float*)d_in[18];
  const float* ln_b = (const float*)d_in[19];
  const float* w_out = (const float*)d_in[20];
  const float* b_out = (const float*)d_in[21];
  float* out = (float*)d_out;
  float* ws = (float*)d_ws;

  const int BLP = B_ * L_ * P_;  // 262144
  const int BLD = B_ * L_ * D_;  // 2097152
  float* m1cT = ws;
  float* m1sT = m1cT + BLP;
  float* qc = m1sT + BLP;
  float* qs = qc + BLP;
  float* sg = qs + BLP;
  float* poff = sg + B_ * L_;
  float* ctxsum = poff + L_ * P_;              // B*64*256 = 65536 floats
  short* UT = (short*)(ctxsum + B_ * 64 * 256);
  short* xbf = UT + (size_t)B_ * NC * 256 * 64;
  short* ctxbf = xbf + BLD;
  short* hs = ctxbf + BLD;            // (unused region, kept for layout)
  short* gvT = hs + BLD;
  short* K2bf = gvT + BLD;            // B*L*64
  short* SPbf = K2bf + B_ * L_ * 64;  // B*L*64
  short* WA = SPbf + B_ * L_ * 64;
  short* W1 = WA + 384 * 256;
  short* WO = W1 + 256 * 512;
  short* W2T = WO + 256 * 256;
  short* W1OT = W2T + 32 * 256;

  wprep<<<3776, 256, 0, stream>>>(x, pos, w_val, w_mem1v, w_off, b_off, w_key, w_gate,
                                  w_sk1, w_out, w_sk2, w_mem1o, WA, W1, WO, W2T, W1OT,
                                  xbf, poff, ctxsum);
  gemmA3<<<512, 384, 0, stream>>>(xbf, WA, pos, poff, b_mem1v, b_key, b_gate, b_val,
                                  m1cT, m1sT, qc, qs, K2bf, gvT, sg);
  scan_all<<<516, 256, 0, stream>>>(m1cT, m1sT, sg, x, ctxsum, ctxbf);
  gemmCD<<<256, 512, 0, stream>>>(xbf, ctxbf, W1, b_sk1, W2T, b_sk2, gvT, SPbf, UT);
  kernelE<<<512, 256, 0, stream>>>(UT);
  fgOut<<<256, 512, 0, stream>>>(UT, SPbf, K2bf, gvT, sg, m1cT, m1sT, qc, qs,
                                 W1OT, b_mem1o, ln_g, ln_b, WO, b_out, x, out);
}

// Round 6
// 168.677 us; speedup vs baseline: 2.4494x; 1.0213x over previous
//
#include <hip/hip_runtime.h>
#include <hip/hip_bf16.h>

constexpr int B_ = 4;
constexpr int L_ = 2048;
constexpr int D_ = 256;
constexpr int P_ = 32;
constexpr int CL = 32;   // chunk length for KV scan
constexpr int NC = L_ / CL;  // 64 chunks

#define PI_F 3.14159265358979323846f
#define INV_SQRT_P 0.17677669529663687f  // 1/sqrt(32)

typedef __attribute__((ext_vector_type(8))) short short8_t;
typedef __attribute__((ext_vector_type(4))) float floatx4;

static __device__ inline short f2bf(float f) {
  unsigned int u;
  __builtin_memcpy(&u, &f, 4);
  unsigned int r = (u + 0x7fffu + ((u >> 16) & 1u)) >> 16;
  return (short)r;
}
static __device__ inline float bf2f(short s) {
  unsigned int u = ((unsigned int)(unsigned short)s) << 16;
  float f;
  __builtin_memcpy(&f, &u, 4);
  return f;
}

// ---------------- wprep: weights + single-pass x->(xbf, ctxsum) + poff -----
// Block map: [0,384) WA | [384,896) W1 | [896,1152) WO | [1152,1184) W2T |
// [1184,1216) W1OT | [1216,1472) poff | [1472,1728) ctx+cast (one x pass).
__global__ void wprep(const float* __restrict__ x, const float* __restrict__ pos,
                      const float* __restrict__ w_val, const float* __restrict__ w_mem1v,
                      const float* __restrict__ w_off, const float* __restrict__ b_off,
                      const float* __restrict__ w_key, const float* __restrict__ w_gate,
                      const float* __restrict__ w_sk1, const float* __restrict__ w_out,
                      const float* __restrict__ w_sk2, const float* __restrict__ w_mem1o,
                      short* __restrict__ WA, short* __restrict__ W1,
                      short* __restrict__ WO, short* __restrict__ W2T,
                      short* __restrict__ W1OT,
                      short* __restrict__ xbf, float* __restrict__ poff,
                      float* __restrict__ ctxsum) {
  __shared__ float2 psum[2][128];
  int blk = blockIdx.x, tid = threadIdx.x;
  if (blk < 384) {
    int idx = blk * 256 + tid;
    int n = idx >> 8, k = idx & 255;
    float v;
    if (n < 256) v = w_val[k * 256 + n];
    else if (n < 288) v = w_mem1v[k * 32 + (n - 256)];
    else if (n < 320) v = w_off[k * 32 + (n - 288)];
    else if (n < 352) v = w_key[k * 32 + (n - 320)];
    else if (n == 352) v = w_gate[k];
    else v = 0.f;
    WA[idx] = f2bf(v);
  } else if (blk < 896) {
    int idx = (blk - 384) * 256 + tid;
    int n = idx >> 9, k = idx & 511;
    W1[idx] = f2bf(w_sk1[k * 256 + n]);
  } else if (blk < 1152) {
    int idx = (blk - 896) * 256 + tid;
    int n = idx >> 8, k = idx & 255;
    WO[idx] = f2bf(w_out[k * 256 + n]);
  } else if (blk < 1184) {
    int idx = (blk - 1152) * 256 + tid;  // p*256 + k
    int p = idx >> 8, k = idx & 255;
    W2T[idx] = f2bf(w_sk2[k * 32 + p]);
  } else if (blk < 1216) {
    int idx = (blk - 1184) * 256 + tid;  // d*32 + p
    int d = idx >> 5, p = idx & 31;
    W1OT[idx] = f2bf(w_mem1o[p * 256 + d]);
  } else if (blk < 1472) {
    int idx = (blk - 1216) * 256 + tid;
    int l = idx >> 5, p = idx & 31;
    float a = b_off[p];
#pragma unroll 8
    for (int j = 0; j < 32; ++j) a += pos[l * 32 + j] * w_off[(256 + j) * 32 + p];
    poff[idx] = a;
  } else {
    // single x pass: cast to xbf AND produce per-chunk d-sums (ctxsum)
    int c2 = blk - 1472;                 // 0..255 = (b, chunk)
    int b = c2 >> 6, ch = c2 & 63;
    int d2 = (tid & 127) * 2, h = tid >> 7;
    int tokb = b * L_ + ch * 32 + h * 16;
    float2 xv[16];
#pragma unroll
    for (int i = 0; i < 16; ++i)
      xv[i] = *(const float2*)&x[(tokb + i) * 256 + d2];
    float2 s = {0.f, 0.f};
#pragma unroll
    for (int i = 0; i < 16; ++i) { s.x += xv[i].x; s.y += xv[i].y; }
#pragma unroll
    for (int i = 0; i < 16; ++i) {
      short2 o;
      o.x = f2bf(xv[i].x);
      o.y = f2bf(xv[i].y);
      *(short2*)&xbf[(tokb + i) * 256 + d2] = o;
    }
    psum[h][tid & 127] = s;
    __syncthreads();
    if (h == 0) {
      float2 o = psum[1][tid & 127];
      float2 tot = {s.x + o.x, s.y + o.y};
      *(float2*)&ctxsum[c2 * 256 + d2] = tot;
    }
  }
}

// ---------------- gemmA3: fused gemm1 (Y = xbf@WA) + kernelA3 epilogue -----
// 512 blocks x 16-token chunks (384 threads, 6 waves) -> 3 waves/SIMD.
__global__ __launch_bounds__(384, 3) void gemmA3(const short* __restrict__ xbf,
                                                 const short* __restrict__ WA,
                                                 const float* __restrict__ pos,
                                                 const float* __restrict__ poff,
                                                 const float* __restrict__ b_mem1v,
                                                 const float* __restrict__ b_key,
                                                 const float* __restrict__ b_gate,
                                                 const float* __restrict__ b_val,
                                                 float* __restrict__ m1cT,
                                                 float* __restrict__ m1sT,
                                                 float* __restrict__ qc,
                                                 float* __restrict__ qs,
                                                 short* __restrict__ K2bf,
                                                 short* __restrict__ gvT,
                                                 float* __restrict__ sg) {
  __shared__ float YL[16][132];  // cols 256..383 of Y, fp32
  __shared__ float gsh[16];
  int tid = threadIdx.x;
  int lane = tid & 63, w = tid >> 6;
  int ml = lane & 15, quad = lane >> 4, kq = quad * 8;
  int bc = blockIdx.x;           // 16-token chunk
  int bc32 = bc >> 1, half = bc & 1;
  int tok0 = bc * 16;
  floatx4 acc[4] = {};
  const short* A0p = &xbf[(tok0 + ml) * 256 + kq];
  const short* Bp = &WA[(w * 64 + ml) * 256 + kq];
#pragma unroll
  for (int ks = 0; ks < 8; ++ks) {
    short8_t a0 = *(const short8_t*)(A0p + ks * 32);
#pragma unroll
    for (int nt = 0; nt < 4; ++nt) {
      short8_t b = *(const short8_t*)(Bp + nt * 16 * 256 + ks * 32);
      acc[nt] = __builtin_amdgcn_mfma_f32_16x16x32_bf16(a0, b, acc[nt], 0, 0, 0);
    }
  }
  // waves 4,5 stage cols 256..383 into LDS (fp32, no bf16 round-trip)
  if (w >= 4) {
#pragma unroll
    for (int nt = 0; nt < 4; ++nt) {
      int col = (w - 4) * 64 + nt * 16 + ml;
#pragma unroll
      for (int r = 0; r < 4; ++r)
        YL[quad * 4 + r][col] = acc[nt][r];
    }
  }
  __syncthreads();
  // A3 elementwise phase: 16 tok x 32 p = 512 items on threads 0..255
  if (tid < 256) {
#pragma unroll
    for (int it = 0; it < 2; ++it) {
      int idx = it * 256 + tid;
      int t = idx >> 5, p = idx & 31;
      int tok = tok0 + t, l = tok & (L_ - 1);
      int b = tok >> 11;
      float v1 = YL[t][p] + b_mem1v[p];
      float ph = pos[l * 32 + p];
      float pc = cosf(ph), ps = sinf(ph);
      int idxT = (b * 32 + p) * L_ + l;
      m1cT[idxT] = pc * v1;
      m1sT[idxT] = ps * v1;
      float off = tanhf(YL[t][32 + p] + poff[l * 32 + p]) * PI_F;
      float oc = cosf(off), os = sinf(off);
      int gidx = tok * 32 + p;
      qc[gidx] = pc * oc - ps * os;
      qs[gidx] = ps * oc + pc * os;
      float kp = tanhf(YL[t][64 + p] + b_key[p]) * PI_F;
      K2bf[tok * 64 + p] = f2bf(cosf(kp));
      K2bf[tok * 64 + 32 + p] = f2bf(sinf(kp));
      if (p == 0) {
        float g = 1.f / (1.f + expf(-(YL[t][96] + b_gate[0])));
        sg[tok] = g;
        gsh[t] = g;
      }
    }
  }
  __syncthreads();
  // gvT = (values + b_val) * gate, [bc32][d][t32] with t-slot = half*16+t
  if (w < 4) {
#pragma unroll
    for (int nt = 0; nt < 4; ++nt) {
      int d = w * 64 + nt * 16 + ml;
      float bv = b_val[d];
      int t0 = quad * 4;
      short4 o;
      o.x = f2bf((acc[nt][0] + bv) * gsh[t0 + 0]);
      o.y = f2bf((acc[nt][1] + bv) * gsh[t0 + 1]);
      o.z = f2bf((acc[nt][2] + bv) * gsh[t0 + 2]);
      o.w = f2bf((acc[nt][3] + bv) * gsh[t0 + 3]);
      *(short4*)&gvT[(bc32 * 256 + d) * 32 + half * 16 + t0] = o;
    }
  }
}

// ---------------- scan_all: m1 + sg scans, 1 barrier -----------------------
// 260 blocks. Wave w owns contiguous segment [w*512, w*512+512): local serial
// scan in registers, single cross-wave offset fix-up.
__global__ void scan_all(float* __restrict__ m1cT, float* __restrict__ m1sT,
                         float* __restrict__ sg) {
  __shared__ float wsum[4];
  int blk = blockIdx.x;
  int tid = threadIdx.x;
  int lane = tid & 63, w = tid >> 6;
  float* arr;
  int base;
  if (blk < 256) {
    arr = (blk < 128) ? m1cT : m1sT;
    base = (blk & 127) * L_;
  } else {
    arr = sg;
    base = (blk - 256) * L_;
  }
  int sbase = base + w * 512;
  float v[8];
#pragma unroll
  for (int i = 0; i < 8; ++i) v[i] = arr[sbase + i * 64 + lane];
  float carry = 0.f;
#pragma unroll
  for (int i = 0; i < 8; ++i) {
    float vv = v[i];
#pragma unroll
    for (int off = 1; off < 64; off <<= 1) {
      float n = __shfl_up(vv, off, 64);
      if (lane >= off) vv += n;
    }
    vv += carry;
    v[i] = vv;
    carry = __shfl(vv, 63, 64);
  }
  if (lane == 0) wsum[w] = carry;
  __syncthreads();
  float off = 0.f;
  for (int ww = 0; ww < w; ++ww) off += wsum[ww];
#pragma unroll
  for (int i = 0; i < 8; ++i) arr[sbase + i * 64 + lane] = v[i] + off;
}

// ---------------- gemmCD: ctx-in-LDS + gemm1 (hs in LDS) + kernelCD --------
union __align__(16) CDMem {
  short As[32][520];                           // A tile [xbf | ctx], K=512
  struct { short HS[32][280]; short SPL[64][40]; } h;
};
__global__ __launch_bounds__(512, 4) void gemmCD(const short* __restrict__ xbf,
                                                 const float* __restrict__ x,
                                                 const float* __restrict__ ctxsum,
                                                 const short* __restrict__ W1,
                                                 const float* __restrict__ b_sk1,
                                                 const short* __restrict__ W2T,
                                                 const float* __restrict__ b_sk2,
                                                 const short* __restrict__ gvT,
                                                 short* __restrict__ SPbf,
                                                 short* __restrict__ UT) {
  __shared__ CDMem sm;
  __shared__ float stmp[256];
  int tid = threadIdx.x;
  int bc = blockIdx.x;
  int tok0 = bc * 32;
  int bI = bc >> 6, ch = bc & 63;
  int lane = tid & 63, w = tid >> 6;
  int ml = lane & 15, quad = lane >> 4, kq = quad * 8;
  // stage xbf half of A (cols 0..255): 1024 short8 over 512 threads
#pragma unroll
  for (int pass = 0; pass < 2; ++pass) {
    int idx = pass * 512 + tid;
    int row = idx >> 5, c8 = idx & 31;
    *(short8_t*)&sm.As[row][c8 * 8] =
        *(const short8_t*)&xbf[(tok0 + row) * 256 + c8 * 8];
  }
  // ctx half (cols 256..511): chunk prefix + local scan, token-halves split
  {
    int d = tid & 255, h = tid >> 8;
    float cp = 0.f;
    int sb = bI * 64 * 256 + d;
    int c = 0;
    for (; c + 8 <= ch; c += 8) {
      float t0 = ctxsum[sb + (c + 0) * 256];
      float t1 = ctxsum[sb + (c + 1) * 256];
      float t2 = ctxsum[sb + (c + 2) * 256];
      float t3 = ctxsum[sb + (c + 3) * 256];
      float t4 = ctxsum[sb + (c + 4) * 256];
      float t5 = ctxsum[sb + (c + 5) * 256];
      float t6 = ctxsum[sb + (c + 6) * 256];
      float t7 = ctxsum[sb + (c + 7) * 256];
      cp += ((t0 + t1) + (t2 + t3)) + ((t4 + t5) + (t6 + t7));
    }
    for (; c < ch; ++c) cp += ctxsum[sb + c * 256];
    float xv[16];
    int xb = (tok0 + h * 16) * 256 + d;
#pragma unroll
    for (int i = 0; i < 16; ++i) xv[i] = x[xb + i * 256];
    float p = 0.f;
#pragma unroll
    for (int i = 0; i < 16; ++i) p += xv[i];
    if (h == 0) stmp[d] = p;
    __syncthreads();
    float run = cp + (h ? stmp[d] : 0.f);
    int l0 = ch * 32 + h * 16;
#pragma unroll
    for (int i = 0; i < 16; ++i) {
      run += xv[i];
      sm.As[h * 16 + i][256 + d] = f2bf(run / (float)(l0 + i + 1));
    }
  }
  __syncthreads();
  // hs = gelu(A @ W1 + b_sk1); wave w owns n-cols [w*32, w*32+32)
  int n0w = w * 32;
  floatx4 acc[2][2] = {};
#pragma unroll
  for (int kt = 0; kt < 16; ++kt) {
    short8_t a0 = *(short8_t*)&sm.As[ml][kt * 32 + kq];
    short8_t a1 = *(short8_t*)&sm.As[16 + ml][kt * 32 + kq];
    short8_t b0 = *(const short8_t*)&W1[(n0w + ml) * 512 + kt * 32 + kq];
    short8_t b1 = *(const short8_t*)&W1[(n0w + 16 + ml) * 512 + kt * 32 + kq];
    acc[0][0] = __builtin_amdgcn_mfma_f32_16x16x32_bf16(a0, b0, acc[0][0], 0, 0, 0);
    acc[0][1] = __builtin_amdgcn_mfma_f32_16x16x32_bf16(a0, b1, acc[0][1], 0, 0, 0);
    acc[1][0] = __builtin_amdgcn_mfma_f32_16x16x32_bf16(a1, b0, acc[1][0], 0, 0, 0);
    acc[1][1] = __builtin_amdgcn_mfma_f32_16x16x32_bf16(a1, b1, acc[1][1], 0, 0, 0);
  }
  short hv[2][2][4];
#pragma unroll
  for (int nt = 0; nt < 2; ++nt) {
    float bv = b_sk1[n0w + nt * 16 + ml];
#pragma unroll
    for (int mt = 0; mt < 2; ++mt)
#pragma unroll
      for (int r = 0; r < 4; ++r) {
        float v = acc[mt][nt][r] + bv;
        float g = 0.5f * v * (1.f + erff(v * 0.70710678118654752f));
        hv[mt][nt][r] = f2bf(g);
      }
  }
  __syncthreads();  // As dead; HS aliases it
#pragma unroll
  for (int mt = 0; mt < 2; ++mt)
#pragma unroll
    for (int nt = 0; nt < 2; ++nt)
#pragma unroll
      for (int r = 0; r < 4; ++r)
        sm.h.HS[mt * 16 + quad * 4 + r][n0w + nt * 16 + ml] = hv[mt][nt][r];
  __syncthreads();
  // Phase B (waves 0..3): SP = tanh(hs @ W2T + b_sk2)*pi -> SPL + SPbf
  if (w < 4) {
    int th = w & 1, ph = w >> 1;
    floatx4 pacc = {};
#pragma unroll
    for (int s = 0; s < 8; ++s) {
      short8_t a = *(short8_t*)&sm.h.HS[th * 16 + ml][s * 32 + kq];
      short8_t b0 = *(const short8_t*)&W2T[(ph * 16 + ml) * 256 + s * 32 + kq];
      pacc = __builtin_amdgcn_mfma_f32_16x16x32_bf16(a, b0, pacc, 0, 0, 0);
    }
    int p = ph * 16 + ml;
    float bs = b_sk2[p];
#pragma unroll
    for (int r = 0; r < 4; ++r) {
      int tl = th * 16 + quad * 4 + r;
      int tok = tok0 + tl;
      float sp = tanhf(pacc[r] + bs) * PI_F;
      short c = f2bf(cosf(sp)), s2 = f2bf(sinf(sp));
      sm.h.SPL[p][tl] = c;
      sm.h.SPL[32 + p][tl] = s2;
      SPbf[tok * 64 + p] = c;
      SPbf[tok * 64 + 32 + p] = s2;
    }
  }
  __syncthreads();
  // Phase C: U chunk sums; wave w owns d in [w*32, w*32+32)
  short8_t a[4];
#pragma unroll
  for (int mt = 0; mt < 4; ++mt) a[mt] = *(short8_t*)&sm.h.SPL[mt * 16 + ml][kq];
  floatx4 acc3[4][2] = {};
#pragma unroll
  for (int nt = 0; nt < 2; ++nt) {
    int d = w * 32 + nt * 16 + ml;
    short8_t b = *(const short8_t*)&gvT[(bc * 256 + d) * 32 + kq];
#pragma unroll
    for (int mt = 0; mt < 4; ++mt)
      acc3[mt][nt] = __builtin_amdgcn_mfma_f32_16x16x32_bf16(a[mt], b, acc3[mt][nt], 0, 0, 0);
  }
#pragma unroll
  for (int mt = 0; mt < 4; ++mt)
#pragma unroll
    for (int nt = 0; nt < 2; ++nt) {
      int d = w * 32 + nt * 16 + ml;
      short4 o;
      o.x = f2bf(acc3[mt][nt][0]);
      o.y = f2bf(acc3[mt][nt][1]);
      o.z = f2bf(acc3[mt][nt][2]);
      o.w = f2bf(acc3[mt][nt][3]);
      *(short4*)&UT[(bc * 256 + d) * 64 + mt * 16 + quad * 4] = o;
    }
}

// ---------------- Kernel E: exclusive chunk prefix, pair-split (2x TLP) ----
__global__ void kernelE(short* __restrict__ UT) {
  int t = blockIdx.x * 256 + threadIdx.x;  // 131072 threads
  int pi = t >> 1, half = t & 1;
  int q = pi & 63;
  int d = (pi >> 6) & 255;
  int b = pi >> 14;
  const int cs = 256 * 64;
  int base = ((b * NC) * 256 + d) * 64 + q + half * 32 * cs;
  short v[32];
#pragma unroll
  for (int c = 0; c < 32; ++c) v[c] = UT[base + c * cs];
  float tot = 0.f;
#pragma unroll
  for (int c = 0; c < 32; ++c) tot += bf2f(v[c]);
  float other = __shfl_xor(tot, 1, 64);
  float run = half ? other : 0.f;
#pragma unroll
  for (int c = 0; c < 32; ++c) {
    UT[base + c * cs] = f2bf(run);
    run += bf2f(v[c]);
  }
}

// ---------------- fgOut: retrieval + pos_out + LN + gemm2 -> out -----------
// Wave 0 computes S concurrently with waves 1-7 doing PR prep (one barrier).
struct __align__(16) FGMem {
  short SL[32][40];
  short PR[32][40];
  float CMB[32][260];
  short CBN[32][280];
  float LG[256], LB[256];
  float scl[32], mu_s[32], rs_s[32];
};
__global__ __launch_bounds__(512, 4) void fgOut(const short* __restrict__ UT,
                                                const short* __restrict__ SPbf,
                                                const short* __restrict__ K2bf,
                                                const short* __restrict__ gvT,
                                                const float* __restrict__ sgc,
                                                const float* __restrict__ m1cT,
                                                const float* __restrict__ m1sT,
                                                const float* __restrict__ qc,
                                                const float* __restrict__ qs,
                                                const short* __restrict__ W1OT,
                                                const float* __restrict__ b_mem1o,
                                                const float* __restrict__ ln_g,
                                                const float* __restrict__ ln_b,
                                                const short* __restrict__ WO,
                                                const float* __restrict__ b_out,
                                                const float* __restrict__ x,
                                                float* __restrict__ out) {
  __shared__ FGMem sm;
  int tid5 = threadIdx.x;
  int bc = blockIdx.x;
  int lbase = bc * CL;
  int bb = bc >> 6, lloc = (bc & 63) * 32;
  int lane = tid5 & 63, w = tid5 >> 6;
  int ml = lane & 15, quad = lane >> 4, kq = quad * 8;
  int d0 = w * 32;
  if (tid5 < 32) sm.scl[tid5] = rsqrtf(fmaxf(sgc[lbase + tid5], 1.f)) * INV_SQRT_P;
  if (tid5 >= 256) {
    int d = tid5 - 256;
    sm.LG[d] = ln_g[d];
    sm.LB[d] = ln_b[d];
  }
  short8_t ka0 = *(const short8_t*)&K2bf[(lbase + ml) * 64 + kq];
  short8_t ka1 = *(const short8_t*)&K2bf[(lbase + 16 + ml) * 64 + kq];
  short8_t kb0 = *(const short8_t*)&K2bf[(lbase + ml) * 64 + 32 + kq];
  short8_t kb1 = *(const short8_t*)&K2bf[(lbase + 16 + ml) * 64 + 32 + kq];
  if (w == 0) {
    // S = K2 @ SP^T, mask, write SL
    floatx4 sacc[2][2] = {};
#pragma unroll
    for (int ks2 = 0; ks2 < 2; ++ks2) {
      short8_t a0 = (ks2 == 0) ? ka0 : kb0;
      short8_t a1 = (ks2 == 0) ? ka1 : kb1;
      short8_t b0 = *(const short8_t*)&SPbf[(lbase + ml) * 64 + ks2 * 32 + kq];
      short8_t b1 = *(const short8_t*)&SPbf[(lbase + 16 + ml) * 64 + ks2 * 32 + kq];
      sacc[0][0] = __builtin_amdgcn_mfma_f32_16x16x32_bf16(a0, b0, sacc[0][0], 0, 0, 0);
      sacc[0][1] = __builtin_amdgcn_mfma_f32_16x16x32_bf16(a0, b1, sacc[0][1], 0, 0, 0);
      sacc[1][0] = __builtin_amdgcn_mfma_f32_16x16x32_bf16(a1, b0, sacc[1][0], 0, 0, 0);
      sacc[1][1] = __builtin_amdgcn_mfma_f32_16x16x32_bf16(a1, b1, sacc[1][1], 0, 0, 0);
    }
#pragma unroll
    for (int mt = 0; mt < 2; ++mt)
#pragma unroll
      for (int nt = 0; nt < 2; ++nt)
#pragma unroll
        for (int r = 0; r < 4; ++r) {
          int trow = mt * 16 + quad * 4 + r;
          int scol = nt * 16 + ml;
          float v = (scol <= trow) ? sacc[mt][nt][r] : 0.f;
          sm.SL[trow][scol] = f2bf(v);
        }
  } else {
    // PR prep: 1024 items over 448 threads (waves 1-7)
    int t7 = tid5 - 64;
    for (int i = t7; i < 1024; i += 448) {
      int pp = i >> 5, t = i & 31;
      int gT = (bb * 32 + pp) * L_ + lloc + t;
      int g = (lbase + t) * 32 + pp;
      sm.PR[t][pp] = f2bf((m1cT[gT] * qc[g] + m1sT[gT] * qs[g]) * INV_SQRT_P);
    }
  }
  __syncthreads();
  // Part 1: K2 @ Uprev (both k-halves)
  floatx4 acc[2][2] = {};
#pragma unroll
  for (int nt = 0; nt < 2; ++nt) {
    short8_t b0 = *(const short8_t*)&UT[(bc * 256 + d0 + nt * 16 + ml) * 64 + kq];
    short8_t b1 = *(const short8_t*)&UT[(bc * 256 + d0 + nt * 16 + ml) * 64 + 32 + kq];
    acc[0][nt] = __builtin_amdgcn_mfma_f32_16x16x32_bf16(ka0, b0, acc[0][nt], 0, 0, 0);
    acc[1][nt] = __builtin_amdgcn_mfma_f32_16x16x32_bf16(ka1, b0, acc[1][nt], 0, 0, 0);
    acc[0][nt] = __builtin_amdgcn_mfma_f32_16x16x32_bf16(kb0, b1, acc[0][nt], 0, 0, 0);
    acc[1][nt] = __builtin_amdgcn_mfma_f32_16x16x32_bf16(kb1, b1, acc[1][nt], 0, 0, 0);
  }
  // Part 2: S @ gv
  {
    short8_t a0 = *(short8_t*)&sm.SL[ml][kq];
    short8_t a1 = *(short8_t*)&sm.SL[16 + ml][kq];
#pragma unroll
    for (int nt = 0; nt < 2; ++nt) {
      short8_t b = *(const short8_t*)&gvT[(bc * 256 + d0 + nt * 16 + ml) * 32 + kq];
      acc[0][nt] = __builtin_amdgcn_mfma_f32_16x16x32_bf16(a0, b, acc[0][nt], 0, 0, 0);
      acc[1][nt] = __builtin_amdgcn_mfma_f32_16x16x32_bf16(a1, b, acc[1][nt], 0, 0, 0);
    }
  }
  // pos_out MFMA
  floatx4 macc[2][2] = {};
  {
    short8_t a0 = *(short8_t*)&sm.PR[ml][kq];
    short8_t a1 = *(short8_t*)&sm.PR[16 + ml][kq];
#pragma unroll
    for (int nt = 0; nt < 2; ++nt) {
      short8_t b = *(const short8_t*)&W1OT[(d0 + nt * 16 + ml) * 32 + kq];
      macc[0][nt] = __builtin_amdgcn_mfma_f32_16x16x32_bf16(a0, b, macc[0][nt], 0, 0, 0);
      macc[1][nt] = __builtin_amdgcn_mfma_f32_16x16x32_bf16(a1, b, macc[1][nt], 0, 0, 0);
    }
  }
#pragma unroll
  for (int mt = 0; mt < 2; ++mt)
#pragma unroll
    for (int nt = 0; nt < 2; ++nt) {
      int d = d0 + nt * 16 + ml;
      float bm = b_mem1o[d];
#pragma unroll
      for (int r = 0; r < 4; ++r) {
        int t = mt * 16 + quad * 4 + r;
        sm.CMB[t][d] = acc[mt][nt][r] * sm.scl[t] + macc[mt][nt][r] + bm;
      }
    }
  __syncthreads();
  // LN stats
  {
    int t = tid5 >> 4, g = tid5 & 15;
    float s = 0.f, s2 = 0.f;
#pragma unroll
    for (int j = 0; j < 16; ++j) {
      float v = sm.CMB[t][g + j * 16];
      s += v;
      s2 += v * v;
    }
#pragma unroll
    for (int m = 1; m < 16; m <<= 1) {
      s += __shfl_xor(s, m, 64);
      s2 += __shfl_xor(s2, m, 64);
    }
    if (g == 0) {
      float mu = s / (float)D_;
      float var = s2 / (float)D_ - mu * mu;
      sm.mu_s[t] = mu;
      sm.rs_s[t] = rsqrtf(var + 1e-5f);
    }
  }
  __syncthreads();
  // normalize -> CBN (bf16) in LDS
#pragma unroll
  for (int it = 0; it < 16; ++it) {
    int i = it * 512 + tid5;
    int t = i >> 8, d = i & 255;
    sm.CBN[t][d] = f2bf((sm.CMB[t][d] - sm.mu_s[t]) * sm.rs_s[t] * sm.LG[d] + sm.LB[d]);
  }
  __syncthreads();
  // gemm2: out = x + CBN @ WO + b_out; wave w owns n-cols [w*32, +32)
  floatx4 acc2[2][2] = {};
#pragma unroll
  for (int kt = 0; kt < 8; ++kt) {
    short8_t a0 = *(short8_t*)&sm.CBN[ml][kt * 32 + kq];
    short8_t a1 = *(short8_t*)&sm.CBN[16 + ml][kt * 32 + kq];
#pragma unroll
    for (int nt = 0; nt < 2; ++nt) {
      short8_t b = *(const short8_t*)&WO[(d0 + nt * 16 + ml) * 256 + kt * 32 + kq];
      acc2[0][nt] = __builtin_amdgcn_mfma_f32_16x16x32_bf16(a0, b, acc2[0][nt], 0, 0, 0);
      acc2[1][nt] = __builtin_amdgcn_mfma_f32_16x16x32_bf16(a1, b, acc2[1][nt], 0, 0, 0);
    }
  }
#pragma unroll
  for (int nt = 0; nt < 2; ++nt) {
    int n = d0 + nt * 16 + ml;
    float bv = b_out[n];
#pragma unroll
    for (int mt = 0; mt < 2; ++mt)
#pragma unroll
      for (int r = 0; r < 4; ++r) {
        int tok = lbase + mt * 16 + quad * 4 + r;
        out[tok * 256 + n] = x[tok * 256 + n] + acc2[mt][nt][r] + bv;
      }
  }
}

extern "C" void kernel_launch(void* const* d_in, const int* in_sizes, int n_in,
                              void* d_out, int out_size, void* d_ws, size_t ws_size,
                              hipStream_t stream) {
  const float* x = (const float*)d_in[0];
  const float* pos = (const float*)d_in[1];
  const float* w_mem1v = (const float*)d_in[2];
  const float* b_mem1v = (const float*)d_in[3];
  const float* w_mem1o = (const float*)d_in[4];
  const float* b_mem1o = (const float*)d_in[5];
  const float* w_off = (const float*)d_in[6];
  const float* b_off = (const float*)d_in[7];
  const float* w_key = (const float*)d_in[8];
  const float* b_key = (const float*)d_in[9];
  const float* w_val = (const float*)d_in[10];
  const float* b_val = (const float*)d_in[11];
  const float* w_sk1 = (const float*)d_in[12];
  const float* b_sk1 = (const float*)d_in[13];
  const float* w_sk2 = (const float*)d_in[14];
  const float* b_sk2 = (const float*)d_in[15];
  const float* w_gate = (const float*)d_in[16];
  const float* b_gate = (const float*)d_in[17];
  const float* ln_g = (const float*)d_in[18];
  const float* ln_b = (const float*)d_in[19];
  const float* w_out = (const float*)d_in[20];
  const float* b_out = (const float*)d_in[21];
  float* out = (float*)d_out;
  float* ws = (float*)d_ws;

  const int BLP = B_ * L_ * P_;  // 262144
  const int BLD = B_ * L_ * D_;  // 2097152
  float* m1cT = ws;
  float* m1sT = m1cT + BLP;
  float* qc = m1sT + BLP;
  float* qs = qc + BLP;
  float* sg = qs + BLP;
  float* poff = sg + B_ * L_;
  float* ctxsum = poff + L_ * P_;              // B*64*256 = 65536 floats
  short* UT = (short*)(ctxsum + B_ * 64 * 256);
  short* xbf = UT + (size_t)B_ * NC * 256 * 64;
  short* ctxbf = xbf + BLD;           // unused (kept for layout stability)
  short* hs = ctxbf + BLD;            // unused (kept for layout stability)
  short* gvT = hs + BLD;
  short* K2bf = gvT + BLD;            // B*L*64
  short* SPbf = K2bf + B_ * L_ * 64;  // B*L*64
  short* WA = SPbf + B_ * L_ * 64;
  short* W1 = WA + 384 * 256;
  short* WO = W1 + 256 * 512;
  short* W2T = WO + 256 * 256;
  short* W1OT = W2T + 32 * 256;

  wprep<<<1728, 256, 0, stream>>>(x, pos, w_val, w_mem1v, w_off, b_off, w_key, w_gate,
                                  w_sk1, w_out, w_sk2, w_mem1o, WA, W1, WO, W2T, W1OT,
                                  xbf, poff, ctxsum);
  gemmA3<<<512, 384, 0, stream>>>(xbf, WA, pos, poff, b_mem1v, b_key, b_gate, b_val,
                                  m1cT, m1sT, qc, qs, K2bf, gvT, sg);
  gemmCD<<<256, 512, 0, stream>>>(xbf, x, ctxsum, W1, b_sk1, W2T, b_sk2, gvT, SPbf, UT);
  kernelE<<<512, 256, 0, stream>>>(UT);
  scan_all<<<260, 256, 0, stream>>>(m1cT, m1sT, sg);
  fgOut<<<256, 512, 0, stream>>>(UT, SPbf, K2bf, gvT, sg, m1cT, m1sT, qc, qs,
                                 W1OT, b_mem1o, ln_g, ln_b, WO, b_out, x, out);
}

// Round 7
// 166.139 us; speedup vs baseline: 2.4868x; 1.0153x over previous
//
#include <hip/hip_runtime.h>
#include <hip/hip_bf16.h>

constexpr int B_ = 4;
constexpr int L_ = 2048;
constexpr int D_ = 256;
constexpr int P_ = 32;
constexpr int CL = 32;   // chunk length for KV scan
constexpr int NC = L_ / CL;  // 64 chunks

#define PI_F 3.14159265358979323846f
#define INV_SQRT_P 0.17677669529663687f  // 1/sqrt(32)

typedef __attribute__((ext_vector_type(8))) short short8_t;
typedef __attribute__((ext_vector_type(4))) float floatx4;

static __device__ inline short f2bf(float f) {
  unsigned int u;
  __builtin_memcpy(&u, &f, 4);
  unsigned int r = (u + 0x7fffu + ((u >> 16) & 1u)) >> 16;
  return (short)r;
}
static __device__ inline float bf2f(short s) {
  unsigned int u = ((unsigned int)(unsigned short)s) << 16;
  float f;
  __builtin_memcpy(&f, &u, 4);
  return f;
}

// ---------------- wprep: weights + single-pass x->(xbf, ctxsum) + poff -----
__global__ void wprep(const float* __restrict__ x, const float* __restrict__ pos,
                      const float* __restrict__ w_val, const float* __restrict__ w_mem1v,
                      const float* __restrict__ w_off, const float* __restrict__ b_off,
                      const float* __restrict__ w_key, const float* __restrict__ w_gate,
                      const float* __restrict__ w_sk1, const float* __restrict__ w_out,
                      const float* __restrict__ w_sk2, const float* __restrict__ w_mem1o,
                      short* __restrict__ WA, short* __restrict__ W1,
                      short* __restrict__ WO, short* __restrict__ W2T,
                      short* __restrict__ W1OT,
                      short* __restrict__ xbf, float* __restrict__ poff,
                      float* __restrict__ ctxsum) {
  __shared__ float2 psum[2][128];
  int blk = blockIdx.x, tid = threadIdx.x;
  if (blk < 384) {
    int idx = blk * 256 + tid;
    int n = idx >> 8, k = idx & 255;
    float v;
    if (n < 256) v = w_val[k * 256 + n];
    else if (n < 288) v = w_mem1v[k * 32 + (n - 256)];
    else if (n < 320) v = w_off[k * 32 + (n - 288)];
    else if (n < 352) v = w_key[k * 32 + (n - 320)];
    else if (n == 352) v = w_gate[k];
    else v = 0.f;
    WA[idx] = f2bf(v);
  } else if (blk < 896) {
    int idx = (blk - 384) * 256 + tid;
    int n = idx >> 9, k = idx & 511;
    W1[idx] = f2bf(w_sk1[k * 256 + n]);
  } else if (blk < 1152) {
    int idx = (blk - 896) * 256 + tid;
    int n = idx >> 8, k = idx & 255;
    WO[idx] = f2bf(w_out[k * 256 + n]);
  } else if (blk < 1184) {
    int idx = (blk - 1152) * 256 + tid;  // p*256 + k
    int p = idx >> 8, k = idx & 255;
    W2T[idx] = f2bf(w_sk2[k * 32 + p]);
  } else if (blk < 1216) {
    int idx = (blk - 1184) * 256 + tid;  // d*32 + p
    int d = idx >> 5, p = idx & 31;
    W1OT[idx] = f2bf(w_mem1o[p * 256 + d]);
  } else if (blk < 1472) {
    int idx = (blk - 1216) * 256 + tid;
    int l = idx >> 5, p = idx & 31;
    float a = b_off[p];
#pragma unroll 8
    for (int j = 0; j < 32; ++j) a += pos[l * 32 + j] * w_off[(256 + j) * 32 + p];
    poff[idx] = a;
  } else {
    // single x pass: cast to xbf AND produce per-chunk d-sums (ctxsum)
    int c2 = blk - 1472;                 // 0..255 = (b, chunk)
    int b = c2 >> 6, ch = c2 & 63;
    int d2 = (tid & 127) * 2, h = tid >> 7;
    int tokb = b * L_ + ch * 32 + h * 16;
    float2 xv[16];
#pragma unroll
    for (int i = 0; i < 16; ++i)
      xv[i] = *(const float2*)&x[(tokb + i) * 256 + d2];
    float2 s = {0.f, 0.f};
#pragma unroll
    for (int i = 0; i < 16; ++i) { s.x += xv[i].x; s.y += xv[i].y; }
#pragma unroll
    for (int i = 0; i < 16; ++i) {
      short2 o;
      o.x = f2bf(xv[i].x);
      o.y = f2bf(xv[i].y);
      *(short2*)&xbf[(tokb + i) * 256 + d2] = o;
    }
    psum[h][tid & 127] = s;
    __syncthreads();
    if (h == 0) {
      float2 o = psum[1][tid & 127];
      float2 tot = {s.x + o.x, s.y + o.y};
      *(float2*)&ctxsum[c2 * 256 + d2] = tot;
    }
  }
}

// ---------------- gemmA3: fused gemm1 (Y = xbf@WA) + kernelA3 epilogue -----
// 512 blocks x 16-token chunks, 768 threads (12 waves) -> 6 waves/SIMD.
// Wave w owns 32 output cols [w*32, w*32+32).
__global__ __launch_bounds__(768, 6) void gemmA3(const short* __restrict__ xbf,
                                                 const short* __restrict__ WA,
                                                 const float* __restrict__ pos,
                                                 const float* __restrict__ poff,
                                                 const float* __restrict__ b_mem1v,
                                                 const float* __restrict__ b_key,
                                                 const float* __restrict__ b_gate,
                                                 const float* __restrict__ b_val,
                                                 float* __restrict__ m1cT,
                                                 float* __restrict__ m1sT,
                                                 float* __restrict__ qc,
                                                 float* __restrict__ qs,
                                                 short* __restrict__ K2bf,
                                                 short* __restrict__ gvT,
                                                 float* __restrict__ sg) {
  __shared__ float YL[16][132];  // cols 256..383 of Y, fp32
  __shared__ float gsh[16];
  int tid = threadIdx.x;
  int lane = tid & 63, w = tid >> 6;
  int ml = lane & 15, quad = lane >> 4, kq = quad * 8;
  int bc = blockIdx.x;           // 16-token chunk
  int bc32 = bc >> 1, half = bc & 1;
  int tok0 = bc * 16;
  floatx4 acc[2] = {};
  const short* A0p = &xbf[(tok0 + ml) * 256 + kq];
  const short* Bp = &WA[(w * 32 + ml) * 256 + kq];
#pragma unroll
  for (int ks = 0; ks < 8; ++ks) {
    short8_t a0 = *(const short8_t*)(A0p + ks * 32);
#pragma unroll
    for (int nt = 0; nt < 2; ++nt) {
      short8_t b = *(const short8_t*)(Bp + nt * 16 * 256 + ks * 32);
      acc[nt] = __builtin_amdgcn_mfma_f32_16x16x32_bf16(a0, b, acc[nt], 0, 0, 0);
    }
  }
  // waves 8..11 stage cols 256..383 into LDS (fp32)
  if (w >= 8) {
#pragma unroll
    for (int nt = 0; nt < 2; ++nt) {
      int col = (w - 8) * 32 + nt * 16 + ml;
#pragma unroll
      for (int r = 0; r < 4; ++r)
        YL[quad * 4 + r][col] = acc[nt][r];
    }
  }
  __syncthreads();
  // A3 elementwise phase: 16 tok x 32 p = 512 items on threads 0..511
  if (tid < 512) {
    int t = tid >> 5, p = tid & 31;
    int tok = tok0 + t, l = tok & (L_ - 1);
    int b = tok >> 11;
    float v1 = YL[t][p] + b_mem1v[p];
    float ph = pos[l * 32 + p];
    float pc = cosf(ph), ps = sinf(ph);
    int idxT = (b * 32 + p) * L_ + l;
    m1cT[idxT] = pc * v1;
    m1sT[idxT] = ps * v1;
    float off = tanhf(YL[t][32 + p] + poff[l * 32 + p]) * PI_F;
    float oc = cosf(off), os = sinf(off);
    int gidx = tok * 32 + p;
    qc[gidx] = pc * oc - ps * os;
    qs[gidx] = ps * oc + pc * os;
    float kp = tanhf(YL[t][64 + p] + b_key[p]) * PI_F;
    K2bf[tok * 64 + p] = f2bf(cosf(kp));
    K2bf[tok * 64 + 32 + p] = f2bf(sinf(kp));
    if (p == 0) {
      float g = 1.f / (1.f + expf(-(YL[t][96] + b_gate[0])));
      sg[tok] = g;
      gsh[t] = g;
    }
  }
  __syncthreads();
  // gvT = (values + b_val) * gate; waves 0..7 own d cols < 256
  if (w < 8) {
#pragma unroll
    for (int nt = 0; nt < 2; ++nt) {
      int d = w * 32 + nt * 16 + ml;
      float bv = b_val[d];
      int t0 = quad * 4;
      short4 o;
      o.x = f2bf((acc[nt][0] + bv) * gsh[t0 + 0]);
      o.y = f2bf((acc[nt][1] + bv) * gsh[t0 + 1]);
      o.z = f2bf((acc[nt][2] + bv) * gsh[t0 + 2]);
      o.w = f2bf((acc[nt][3] + bv) * gsh[t0 + 3]);
      *(short4*)&gvT[(bc32 * 256 + d) * 32 + half * 16 + t0] = o;
    }
  }
}

// ---------------- scan_all: m1 + sg scans + ctxsum chunk prefix ------------
// Blocks 0..259: token scans (1 barrier). Blocks 260..263: in-place exclusive
// prefix of ctxsum over the 64 chunks (per (b,d)) so gemmCD reads ONE value.
__global__ void scan_all(float* __restrict__ m1cT, float* __restrict__ m1sT,
                         float* __restrict__ sg, float* __restrict__ ctxsum) {
  int blk = blockIdx.x;
  int tid = threadIdx.x;
  if (blk >= 260) {
    int b = blk - 260;
    int base = b * 64 * 256 + tid;
    float v[64];
#pragma unroll
    for (int c = 0; c < 64; ++c) v[c] = ctxsum[base + c * 256];
    float run = 0.f;
#pragma unroll
    for (int c = 0; c < 64; ++c) {
      ctxsum[base + c * 256] = run;
      run += v[c];
    }
    return;
  }
  __shared__ float wsum[4];
  int lane = tid & 63, w = tid >> 6;
  float* arr;
  int base;
  if (blk < 256) {
    arr = (blk < 128) ? m1cT : m1sT;
    base = (blk & 127) * L_;
  } else {
    arr = sg;
    base = (blk - 256) * L_;
  }
  int sbase = base + w * 512;
  float v[8];
#pragma unroll
  for (int i = 0; i < 8; ++i) v[i] = arr[sbase + i * 64 + lane];
  float carry = 0.f;
#pragma unroll
  for (int i = 0; i < 8; ++i) {
    float vv = v[i];
#pragma unroll
    for (int off = 1; off < 64; off <<= 1) {
      float n = __shfl_up(vv, off, 64);
      if (lane >= off) vv += n;
    }
    vv += carry;
    v[i] = vv;
    carry = __shfl(vv, 63, 64);
  }
  if (lane == 0) wsum[w] = carry;
  __syncthreads();
  float off = 0.f;
  for (int ww = 0; ww < w; ++ww) off += wsum[ww];
#pragma unroll
  for (int i = 0; i < 8; ++i) arr[sbase + i * 64 + lane] = v[i] + off;
}

// ---------------- gemmCD: ctx-in-LDS + gemm1 (hs in LDS) + kernelCD --------
// 256 blocks x 1024 threads (16 waves -> 4 waves/SIMD). Wave w owns 16 cols.
union __align__(16) CDMem {
  short As[32][520];                           // A tile [xbf | ctx], K=512
  struct { short HS[32][280]; short SPL[64][40]; } h;
};
__global__ __launch_bounds__(1024, 4) void gemmCD(const short* __restrict__ xbf,
                                                  const float* __restrict__ x,
                                                  const float* __restrict__ ctxsum,
                                                  const short* __restrict__ W1,
                                                  const float* __restrict__ b_sk1,
                                                  const short* __restrict__ W2T,
                                                  const float* __restrict__ b_sk2,
                                                  const short* __restrict__ gvT,
                                                  short* __restrict__ SPbf,
                                                  short* __restrict__ UT) {
  __shared__ CDMem sm;
  __shared__ float stmp[4][256];
  int tid = threadIdx.x;
  int bc = blockIdx.x;
  int tok0 = bc * 32;
  int bI = bc >> 6, ch = bc & 63;
  int lane = tid & 63, w = tid >> 6;
  int ml = lane & 15, quad = lane >> 4, kq = quad * 8;
  // stage xbf half of A (cols 0..255): 1024 short8, one per thread
  {
    int row = tid >> 5, c8 = tid & 31;
    *(short8_t*)&sm.As[row][c8 * 8] =
        *(const short8_t*)&xbf[(tok0 + row) * 256 + c8 * 8];
  }
  // ctx half (cols 256..511): prefix is ONE load now; 4 token-quarters
  {
    int d = tid & 255, qh = tid >> 8;
    float cp = ctxsum[(bI * 64 + ch) * 256 + d];  // exclusive chunk prefix
    float xv[8];
    int xb = (tok0 + qh * 8) * 256 + d;
#pragma unroll
    for (int i = 0; i < 8; ++i) xv[i] = x[xb + i * 256];
    float p = 0.f;
#pragma unroll
    for (int i = 0; i < 8; ++i) p += xv[i];
    stmp[qh][d] = p;
    __syncthreads();
    float run = cp;
    for (int j = 0; j < qh; ++j) run += stmp[j][d];
    int l0 = ch * 32 + qh * 8;
#pragma unroll
    for (int i = 0; i < 8; ++i) {
      run += xv[i];
      sm.As[qh * 8 + i][256 + d] = f2bf(run / (float)(l0 + i + 1));
    }
  }
  __syncthreads();
  // hs = gelu(A @ W1 + b_sk1); wave w owns n-cols [w*16, w*16+16)
  int n0w = w * 16;
  floatx4 acc[2] = {};
#pragma unroll
  for (int kt = 0; kt < 16; ++kt) {
    short8_t a0 = *(short8_t*)&sm.As[ml][kt * 32 + kq];
    short8_t a1 = *(short8_t*)&sm.As[16 + ml][kt * 32 + kq];
    short8_t b0 = *(const short8_t*)&W1[(n0w + ml) * 512 + kt * 32 + kq];
    acc[0] = __builtin_amdgcn_mfma_f32_16x16x32_bf16(a0, b0, acc[0], 0, 0, 0);
    acc[1] = __builtin_amdgcn_mfma_f32_16x16x32_bf16(a1, b0, acc[1], 0, 0, 0);
  }
  short hv[2][4];
  {
    float bv = b_sk1[n0w + ml];
#pragma unroll
    for (int mt = 0; mt < 2; ++mt)
#pragma unroll
      for (int r = 0; r < 4; ++r) {
        float v = acc[mt][r] + bv;
        float g = 0.5f * v * (1.f + erff(v * 0.70710678118654752f));
        hv[mt][r] = f2bf(g);
      }
  }
  __syncthreads();  // As dead; HS aliases it
#pragma unroll
  for (int mt = 0; mt < 2; ++mt)
#pragma unroll
    for (int r = 0; r < 4; ++r)
      sm.h.HS[mt * 16 + quad * 4 + r][n0w + ml] = hv[mt][r];
  __syncthreads();
  // Phase B (waves 0..3): SP = tanh(hs @ W2T + b_sk2)*pi -> SPL + SPbf
  if (w < 4) {
    int th = w & 1, ph = w >> 1;
    floatx4 pacc = {};
#pragma unroll
    for (int s = 0; s < 8; ++s) {
      short8_t a = *(short8_t*)&sm.h.HS[th * 16 + ml][s * 32 + kq];
      short8_t b0 = *(const short8_t*)&W2T[(ph * 16 + ml) * 256 + s * 32 + kq];
      pacc = __builtin_amdgcn_mfma_f32_16x16x32_bf16(a, b0, pacc, 0, 0, 0);
    }
    int p = ph * 16 + ml;
    float bs = b_sk2[p];
#pragma unroll
    for (int r = 0; r < 4; ++r) {
      int tl = th * 16 + quad * 4 + r;
      int tok = tok0 + tl;
      float sp = tanhf(pacc[r] + bs) * PI_F;
      short c = f2bf(cosf(sp)), s2 = f2bf(sinf(sp));
      sm.h.SPL[p][tl] = c;
      sm.h.SPL[32 + p][tl] = s2;
      SPbf[tok * 64 + p] = c;
      SPbf[tok * 64 + 32 + p] = s2;
    }
  }
  __syncthreads();
  // Phase C: U chunk sums; wave w owns d in [w*16, w*16+16)
  short8_t a[4];
#pragma unroll
  for (int mt = 0; mt < 4; ++mt) a[mt] = *(short8_t*)&sm.h.SPL[mt * 16 + ml][kq];
  floatx4 acc3[4] = {};
  {
    int d = w * 16 + ml;
    short8_t b = *(const short8_t*)&gvT[(bc * 256 + d) * 32 + kq];
#pragma unroll
    for (int mt = 0; mt < 4; ++mt)
      acc3[mt] = __builtin_amdgcn_mfma_f32_16x16x32_bf16(a[mt], b, acc3[mt], 0, 0, 0);
  }
#pragma unroll
  for (int mt = 0; mt < 4; ++mt) {
    int d = w * 16 + ml;
    short4 o;
    o.x = f2bf(acc3[mt][0]);
    o.y = f2bf(acc3[mt][1]);
    o.z = f2bf(acc3[mt][2]);
    o.w = f2bf(acc3[mt][3]);
    *(short4*)&UT[(bc * 256 + d) * 64 + mt * 16 + quad * 4] = o;
  }
}

// ---------------- Kernel E: exclusive chunk prefix, 4-lane split -----------
// Lanes (4i..4i+3) share one (b,d,q): lane j scans chunks [j*16, j*16+16).
__global__ void kernelE(short* __restrict__ UT) {
  int t = blockIdx.x * 256 + threadIdx.x;  // 262144 threads
  int pi = t >> 2, j = t & 3;
  int q = pi & 63;
  int d = (pi >> 6) & 255;
  int b = pi >> 14;
  const int cs = 256 * 64;
  int base = ((b * NC) * 256 + d) * 64 + q + j * 16 * cs;
  short v[16];
#pragma unroll
  for (int c = 0; c < 16; ++c) v[c] = UT[base + c * cs];
  float tot = 0.f;
#pragma unroll
  for (int c = 0; c < 16; ++c) tot += bf2f(v[c]);
  int lane = threadIdx.x & 63;
  int gb = lane & ~3;
  float t0 = __shfl(tot, gb + 0, 64);
  float t1 = __shfl(tot, gb + 1, 64);
  float t2 = __shfl(tot, gb + 2, 64);
  float run = (j > 0 ? t0 : 0.f) + (j > 1 ? t1 : 0.f) + (j > 2 ? t2 : 0.f);
#pragma unroll
  for (int c = 0; c < 16; ++c) {
    UT[base + c * cs] = f2bf(run);
    run += bf2f(v[c]);
  }
}

// ---------------- fgOut: retrieval + pos_out + LN + gemm2 -> out -----------
// 256 blocks x 1024 threads (16 waves -> 4 waves/SIMD); wave w owns 16 cols.
struct __align__(16) FGMem {
  short SL[32][40];
  short PR[32][40];
  float CMB[32][260];
  short CBN[32][280];
  float LG[256], LB[256];
  float scl[32], mu_s[32], rs_s[32];
};
__global__ __launch_bounds__(1024, 4) void fgOut(const short* __restrict__ UT,
                                                 const short* __restrict__ SPbf,
                                                 const short* __restrict__ K2bf,
                                                 const short* __restrict__ gvT,
                                                 const float* __restrict__ sgc,
                                                 const float* __restrict__ m1cT,
                                                 const float* __restrict__ m1sT,
                                                 const float* __restrict__ qc,
                                                 const float* __restrict__ qs,
                                                 const short* __restrict__ W1OT,
                                                 const float* __restrict__ b_mem1o,
                                                 const float* __restrict__ ln_g,
                                                 const float* __restrict__ ln_b,
                                                 const short* __restrict__ WO,
                                                 const float* __restrict__ b_out,
                                                 const float* __restrict__ x,
                                                 float* __restrict__ out) {
  __shared__ FGMem sm;
  int tid5 = threadIdx.x;
  int bc = blockIdx.x;
  int lbase = bc * CL;
  int bb = bc >> 6, lloc = (bc & 63) * 32;
  int lane = tid5 & 63, w = tid5 >> 6;
  int ml = lane & 15, quad = lane >> 4, kq = quad * 8;
  int d0 = w * 16;
  if (tid5 < 32) sm.scl[tid5] = rsqrtf(fmaxf(sgc[lbase + tid5], 1.f)) * INV_SQRT_P;
  if (tid5 >= 256 && tid5 < 512) {
    int d = tid5 - 256;
    sm.LG[d] = ln_g[d];
    sm.LB[d] = ln_b[d];
  }
  short8_t ka0 = *(const short8_t*)&K2bf[(lbase + ml) * 64 + kq];
  short8_t ka1 = *(const short8_t*)&K2bf[(lbase + 16 + ml) * 64 + kq];
  short8_t kb0 = *(const short8_t*)&K2bf[(lbase + ml) * 64 + 32 + kq];
  short8_t kb1 = *(const short8_t*)&K2bf[(lbase + 16 + ml) * 64 + 32 + kq];
  if (w == 0) {
    // S = K2 @ SP^T, mask, write SL
    floatx4 sacc[2][2] = {};
#pragma unroll
    for (int ks2 = 0; ks2 < 2; ++ks2) {
      short8_t a0 = (ks2 == 0) ? ka0 : kb0;
      short8_t a1 = (ks2 == 0) ? ka1 : kb1;
      short8_t b0 = *(const short8_t*)&SPbf[(lbase + ml) * 64 + ks2 * 32 + kq];
      short8_t b1 = *(const short8_t*)&SPbf[(lbase + 16 + ml) * 64 + ks2 * 32 + kq];
      sacc[0][0] = __builtin_amdgcn_mfma_f32_16x16x32_bf16(a0, b0, sacc[0][0], 0, 0, 0);
      sacc[0][1] = __builtin_amdgcn_mfma_f32_16x16x32_bf16(a0, b1, sacc[0][1], 0, 0, 0);
      sacc[1][0] = __builtin_amdgcn_mfma_f32_16x16x32_bf16(a1, b0, sacc[1][0], 0, 0, 0);
      sacc[1][1] = __builtin_amdgcn_mfma_f32_16x16x32_bf16(a1, b1, sacc[1][1], 0, 0, 0);
    }
#pragma unroll
    for (int mt = 0; mt < 2; ++mt)
#pragma unroll
      for (int nt = 0; nt < 2; ++nt)
#pragma unroll
        for (int r = 0; r < 4; ++r) {
          int trow = mt * 16 + quad * 4 + r;
          int scol = nt * 16 + ml;
          float v = (scol <= trow) ? sacc[mt][nt][r] : 0.f;
          sm.SL[trow][scol] = f2bf(v);
        }
  } else {
    // PR prep: 1024 items over 960 threads (waves 1-15)
    int t7 = tid5 - 64;
    for (int i = t7; i < 1024; i += 960) {
      int pp = i >> 5, t = i & 31;
      int gT = (bb * 32 + pp) * L_ + lloc + t;
      int g = (lbase + t) * 32 + pp;
      sm.PR[t][pp] = f2bf((m1cT[gT] * qc[g] + m1sT[gT] * qs[g]) * INV_SQRT_P);
    }
  }
  __syncthreads();
  // Part 1: K2 @ Uprev (both k-halves); wave w owns d [w*16, w*16+16)
  floatx4 acc[2] = {};
  {
    short8_t b0 = *(const short8_t*)&UT[(bc * 256 + d0 + ml) * 64 + kq];
    short8_t b1 = *(const short8_t*)&UT[(bc * 256 + d0 + ml) * 64 + 32 + kq];
    acc[0] = __builtin_amdgcn_mfma_f32_16x16x32_bf16(ka0, b0, acc[0], 0, 0, 0);
    acc[1] = __builtin_amdgcn_mfma_f32_16x16x32_bf16(ka1, b0, acc[1], 0, 0, 0);
    acc[0] = __builtin_amdgcn_mfma_f32_16x16x32_bf16(kb0, b1, acc[0], 0, 0, 0);
    acc[1] = __builtin_amdgcn_mfma_f32_16x16x32_bf16(kb1, b1, acc[1], 0, 0, 0);
  }
  // Part 2: S @ gv
  {
    short8_t a0 = *(short8_t*)&sm.SL[ml][kq];
    short8_t a1 = *(short8_t*)&sm.SL[16 + ml][kq];
    short8_t b = *(const short8_t*)&gvT[(bc * 256 + d0 + ml) * 32 + kq];
    acc[0] = __builtin_amdgcn_mfma_f32_16x16x32_bf16(a0, b, acc[0], 0, 0, 0);
    acc[1] = __builtin_amdgcn_mfma_f32_16x16x32_bf16(a1, b, acc[1], 0, 0, 0);
  }
  // pos_out MFMA
  floatx4 macc[2] = {};
  {
    short8_t a0 = *(short8_t*)&sm.PR[ml][kq];
    short8_t a1 = *(short8_t*)&sm.PR[16 + ml][kq];
    short8_t b = *(const short8_t*)&W1OT[(d0 + ml) * 32 + kq];
    macc[0] = __builtin_amdgcn_mfma_f32_16x16x32_bf16(a0, b, macc[0], 0, 0, 0);
    macc[1] = __builtin_amdgcn_mfma_f32_16x16x32_bf16(a1, b, macc[1], 0, 0, 0);
  }
  {
    int d = d0 + ml;
    float bm = b_mem1o[d];
#pragma unroll
    for (int mt = 0; mt < 2; ++mt)
#pragma unroll
      for (int r = 0; r < 4; ++r) {
        int t = mt * 16 + quad * 4 + r;
        sm.CMB[t][d] = acc[mt][r] * sm.scl[t] + macc[mt][r] + bm;
      }
  }
  __syncthreads();
  // LN stats: 32 threads per token, 8 elements each
  {
    int t = tid5 >> 5, g = tid5 & 31;
    float s = 0.f, s2 = 0.f;
#pragma unroll
    for (int j = 0; j < 8; ++j) {
      float v = sm.CMB[t][g + j * 32];
      s += v;
      s2 += v * v;
    }
#pragma unroll
    for (int m = 1; m < 32; m <<= 1) {
      s += __shfl_xor(s, m, 64);
      s2 += __shfl_xor(s2, m, 64);
    }
    if (g == 0) {
      float mu = s / (float)D_;
      float var = s2 / (float)D_ - mu * mu;
      sm.mu_s[t] = mu;
      sm.rs_s[t] = rsqrtf(var + 1e-5f);
    }
  }
  __syncthreads();
  // normalize -> CBN (bf16) in LDS
#pragma unroll
  for (int it = 0; it < 8; ++it) {
    int i = it * 1024 + tid5;
    int t = i >> 8, d = i & 255;
    sm.CBN[t][d] = f2bf((sm.CMB[t][d] - sm.mu_s[t]) * sm.rs_s[t] * sm.LG[d] + sm.LB[d]);
  }
  __syncthreads();
  // gemm2: out = x + CBN @ WO + b_out; wave w owns n-cols [w*16, +16)
  floatx4 acc2[2] = {};
#pragma unroll
  for (int kt = 0; kt < 8; ++kt) {
    short8_t a0 = *(short8_t*)&sm.CBN[ml][kt * 32 + kq];
    short8_t a1 = *(short8_t*)&sm.CBN[16 + ml][kt * 32 + kq];
    short8_t b = *(const short8_t*)&WO[(d0 + ml) * 256 + kt * 32 + kq];
    acc2[0] = __builtin_amdgcn_mfma_f32_16x16x32_bf16(a0, b, acc2[0], 0, 0, 0);
    acc2[1] = __builtin_amdgcn_mfma_f32_16x16x32_bf16(a1, b, acc2[1], 0, 0, 0);
  }
  {
    int n = d0 + ml;
    float bv = b_out[n];
#pragma unroll
    for (int mt = 0; mt < 2; ++mt)
#pragma unroll
      for (int r = 0; r < 4; ++r) {
        int tok = lbase + mt * 16 + quad * 4 + r;
        out[tok * 256 + n] = x[tok * 256 + n] + acc2[mt][r] + bv;
      }
  }
}

extern "C" void kernel_launch(void* const* d_in, const int* in_sizes, int n_in,
                              void* d_out, int out_size, void* d_ws, size_t ws_size,
                              hipStream_t stream) {
  const float* x = (const float*)d_in[0];
  const float* pos = (const float*)d_in[1];
  const float* w_mem1v = (const float*)d_in[2];
  const float* b_mem1v = (const float*)d_in[3];
  const float* w_mem1o = (const float*)d_in[4];
  const float* b_mem1o = (const float*)d_in[5];
  const float* w_off = (const float*)d_in[6];
  const float* b_off = (const float*)d_in[7];
  const float* w_key = (const float*)d_in[8];
  const float* b_key = (const float*)d_in[9];
  const float* w_val = (const float*)d_in[10];
  const float* b_val = (const float*)d_in[11];
  const float* w_sk1 = (const float*)d_in[12];
  const float* b_sk1 = (const float*)d_in[13];
  const float* w_sk2 = (const float*)d_in[14];
  const float* b_sk2 = (const float*)d_in[15];
  const float* w_gate = (const float*)d_in[16];
  const float* b_gate = (const float*)d_in[17];
  const float* ln_g = (const float*)d_in[18];
  const float* ln_b = (const float*)d_in[19];
  const float* w_out = (const float*)d_in[20];
  const float* b_out = (const float*)d_in[21];
  float* out = (float*)d_out;
  float* ws = (float*)d_ws;

  const int BLP = B_ * L_ * P_;  // 262144
  const int BLD = B_ * L_ * D_;  // 2097152
  float* m1cT = ws;
  float* m1sT = m1cT + BLP;
  float* qc = m1sT + BLP;
  float* qs = qc + BLP;
  float* sg = qs + BLP;
  float* poff = sg + B_ * L_;
  float* ctxsum = poff + L_ * P_;              // B*64*256 = 65536 floats
  short* UT = (short*)(ctxsum + B_ * 64 * 256);
  short* xbf = UT + (size_t)B_ * NC * 256 * 64;
  short* ctxbf = xbf + BLD;           // unused (layout stability)
  short* hs = ctxbf + BLD;            // unused (layout stability)
  short* gvT = hs + BLD;
  short* K2bf = gvT + BLD;            // B*L*64
  short* SPbf = K2bf + B_ * L_ * 64;  // B*L*64
  short* WA = SPbf + B_ * L_ * 64;
  short* W1 = WA + 384 * 256;
  short* WO = W1 + 256 * 512;
  short* W2T = WO + 256 * 256;
  short* W1OT = W2T + 32 * 256;

  wprep<<<1728, 256, 0, stream>>>(x, pos, w_val, w_mem1v, w_off, b_off, w_key, w_gate,
                                  w_sk1, w_out, w_sk2, w_mem1o, WA, W1, WO, W2T, W1OT,
                                  xbf, poff, ctxsum);
  gemmA3<<<512, 768, 0, stream>>>(xbf, WA, pos, poff, b_mem1v, b_key, b_gate, b_val,
                                  m1cT, m1sT, qc, qs, K2bf, gvT, sg);
  scan_all<<<264, 256, 0, stream>>>(m1cT, m1sT, sg, ctxsum);
  gemmCD<<<256, 1024, 0, stream>>>(xbf, x, ctxsum, W1, b_sk1, W2T, b_sk2, gvT, SPbf, UT);
  kernelE<<<1024, 256, 0, stream>>>(UT);
  fgOut<<<256, 1024, 0, stream>>>(UT, SPbf, K2bf, gvT, sg, m1cT, m1sT, qc, qs,
                                  W1OT, b_mem1o, ln_g, ln_b, WO, b_out, x, out);
}

// Round 8
// 162.729 us; speedup vs baseline: 2.5389x; 1.0210x over previous
//
#include <hip/hip_runtime.h>
#include <hip/hip_bf16.h>

constexpr int B_ = 4;
constexpr int L_ = 2048;
constexpr int D_ = 256;
constexpr int P_ = 32;
constexpr int CL = 32;   // chunk length for KV scan
constexpr int NC = L_ / CL;  // 64 chunks

#define PI_F 3.14159265358979323846f
#define INV_SQRT_P 0.17677669529663687f  // 1/sqrt(32)

typedef __attribute__((ext_vector_type(8))) short short8_t;
typedef __attribute__((ext_vector_type(4))) float floatx4;

static __device__ inline short f2bf(float f) {
  unsigned int u;
  __builtin_memcpy(&u, &f, 4);
  unsigned int r = (u + 0x7fffu + ((u >> 16) & 1u)) >> 16;
  return (short)r;
}
static __device__ inline float bf2f(short s) {
  unsigned int u = ((unsigned int)(unsigned short)s) << 16;
  float f;
  __builtin_memcpy(&f, &u, 4);
  return f;
}

// ---------------- wprep: weights + single-pass x->(xbf, ctxsum) + poff -----
__global__ void wprep(const float* __restrict__ x, const float* __restrict__ pos,
                      const float* __restrict__ w_val, const float* __restrict__ w_mem1v,
                      const float* __restrict__ w_off, const float* __restrict__ b_off,
                      const float* __restrict__ w_key, const float* __restrict__ w_gate,
                      const float* __restrict__ w_sk1, const float* __restrict__ w_out,
                      const float* __restrict__ w_sk2, const float* __restrict__ w_mem1o,
                      short* __restrict__ WA, short* __restrict__ W1,
                      short* __restrict__ WO, short* __restrict__ W2T,
                      short* __restrict__ W1OT,
                      short* __restrict__ xbf, float* __restrict__ poff,
                      float* __restrict__ ctxsum) {
  __shared__ float2 psum[2][128];
  int blk = blockIdx.x, tid = threadIdx.x;
  if (blk < 384) {
    int idx = blk * 256 + tid;
    int n = idx >> 8, k = idx & 255;
    float v;
    if (n < 256) v = w_val[k * 256 + n];
    else if (n < 288) v = w_mem1v[k * 32 + (n - 256)];
    else if (n < 320) v = w_off[k * 32 + (n - 288)];
    else if (n < 352) v = w_key[k * 32 + (n - 320)];
    else if (n == 352) v = w_gate[k];
    else v = 0.f;
    WA[idx] = f2bf(v);
  } else if (blk < 896) {
    int idx = (blk - 384) * 256 + tid;
    int n = idx >> 9, k = idx & 511;
    W1[idx] = f2bf(w_sk1[k * 256 + n]);
  } else if (blk < 1152) {
    int idx = (blk - 896) * 256 + tid;
    int n = idx >> 8, k = idx & 255;
    WO[idx] = f2bf(w_out[k * 256 + n]);
  } else if (blk < 1184) {
    int idx = (blk - 1152) * 256 + tid;  // p*256 + k
    int p = idx >> 8, k = idx & 255;
    W2T[idx] = f2bf(w_sk2[k * 32 + p]);
  } else if (blk < 1216) {
    int idx = (blk - 1184) * 256 + tid;  // d*32 + p
    int d = idx >> 5, p = idx & 31;
    W1OT[idx] = f2bf(w_mem1o[p * 256 + d]);
  } else if (blk < 1472) {
    int idx = (blk - 1216) * 256 + tid;
    int l = idx >> 5, p = idx & 31;
    float a = b_off[p];
#pragma unroll 8
    for (int j = 0; j < 32; ++j) a += pos[l * 32 + j] * w_off[(256 + j) * 32 + p];
    poff[idx] = a;
  } else {
    // single x pass: cast to xbf AND produce per-chunk d-sums (ctxsum)
    int c2 = blk - 1472;                 // 0..255 = (b, chunk)
    int b = c2 >> 6, ch = c2 & 63;
    int d2 = (tid & 127) * 2, h = tid >> 7;
    int tokb = b * L_ + ch * 32 + h * 16;
    float2 xv[16];
#pragma unroll
    for (int i = 0; i < 16; ++i)
      xv[i] = *(const float2*)&x[(tokb + i) * 256 + d2];
    float2 s = {0.f, 0.f};
#pragma unroll
    for (int i = 0; i < 16; ++i) { s.x += xv[i].x; s.y += xv[i].y; }
#pragma unroll
    for (int i = 0; i < 16; ++i) {
      short2 o;
      o.x = f2bf(xv[i].x);
      o.y = f2bf(xv[i].y);
      *(short2*)&xbf[(tokb + i) * 256 + d2] = o;
    }
    psum[h][tid & 127] = s;
    __syncthreads();
    if (h == 0) {
      float2 o = psum[1][tid & 127];
      float2 tot = {s.x + o.x, s.y + o.y};
      *(float2*)&ctxsum[c2 * 256 + d2] = tot;
    }
  }
}

// ---------------- gemmA3: fused gemm1 + A3 epilogue + ctx-prefix blocks ----
// Blocks 0..511: 16-token chunks (768 threads, 12 waves -> 6 waves/SIMD).
// Blocks 512..515: in-place exclusive chunk-prefix of ctxsum (hidden under
// the 512 GEMM blocks; depends only on wprep).
__global__ __launch_bounds__(768, 6) void gemmA3(const short* __restrict__ xbf,
                                                 const short* __restrict__ WA,
                                                 const float* __restrict__ pos,
                                                 const float* __restrict__ poff,
                                                 const float* __restrict__ b_mem1v,
                                                 const float* __restrict__ b_key,
                                                 const float* __restrict__ b_gate,
                                                 const float* __restrict__ b_val,
                                                 float* __restrict__ m1cT,
                                                 float* __restrict__ m1sT,
                                                 float* __restrict__ qc,
                                                 float* __restrict__ qs,
                                                 short* __restrict__ K2bf,
                                                 short* __restrict__ gvT,
                                                 float* __restrict__ sg,
                                                 float* __restrict__ ctxsum) {
  __shared__ float YL[16][132];  // cols 256..383 of Y, fp32
  __shared__ float gsh[16];
  int tid = threadIdx.x;
  int bc = blockIdx.x;
  if (bc >= 512) {
    // ctx-prefix: batch-8 loads, exclusive prefix over 64 chunks per (b,d)
    if (tid < 256) {
      int b = bc - 512;
      int base = b * 64 * 256 + tid;
      float run = 0.f;
      for (int c0 = 0; c0 < 64; c0 += 8) {
        float v[8];
#pragma unroll
        for (int j = 0; j < 8; ++j) v[j] = ctxsum[base + (c0 + j) * 256];
#pragma unroll
        for (int j = 0; j < 8; ++j) {
          ctxsum[base + (c0 + j) * 256] = run;
          run += v[j];
        }
      }
    }
    return;
  }
  int lane = tid & 63, w = tid >> 6;
  int ml = lane & 15, quad = lane >> 4, kq = quad * 8;
  int bc32 = bc >> 1, half = bc & 1;
  int tok0 = bc * 16;
  floatx4 acc[2] = {};
  const short* A0p = &xbf[(tok0 + ml) * 256 + kq];
  const short* Bp = &WA[(w * 32 + ml) * 256 + kq];
#pragma unroll
  for (int ks = 0; ks < 8; ++ks) {
    short8_t a0 = *(const short8_t*)(A0p + ks * 32);
#pragma unroll
    for (int nt = 0; nt < 2; ++nt) {
      short8_t b = *(const short8_t*)(Bp + nt * 16 * 256 + ks * 32);
      acc[nt] = __builtin_amdgcn_mfma_f32_16x16x32_bf16(a0, b, acc[nt], 0, 0, 0);
    }
  }
  // waves 8..11 stage cols 256..383 into LDS (fp32)
  if (w >= 8) {
#pragma unroll
    for (int nt = 0; nt < 2; ++nt) {
      int col = (w - 8) * 32 + nt * 16 + ml;
#pragma unroll
      for (int r = 0; r < 4; ++r)
        YL[quad * 4 + r][col] = acc[nt][r];
    }
  }
  __syncthreads();
  // A3 elementwise phase: 16 tok x 32 p = 512 items on threads 0..511
  if (tid < 512) {
    int t = tid >> 5, p = tid & 31;
    int tok = tok0 + t, l = tok & (L_ - 1);
    int b = tok >> 11;
    float v1 = YL[t][p] + b_mem1v[p];
    float ph = pos[l * 32 + p];
    float pc = cosf(ph), ps = sinf(ph);
    int idxT = (b * 32 + p) * L_ + l;
    m1cT[idxT] = pc * v1;
    m1sT[idxT] = ps * v1;
    float off = tanhf(YL[t][32 + p] + poff[l * 32 + p]) * PI_F;
    float oc = cosf(off), os = sinf(off);
    int gidx = tok * 32 + p;
    qc[gidx] = pc * oc - ps * os;
    qs[gidx] = ps * oc + pc * os;
    float kp = tanhf(YL[t][64 + p] + b_key[p]) * PI_F;
    K2bf[tok * 64 + p] = f2bf(cosf(kp));
    K2bf[tok * 64 + 32 + p] = f2bf(sinf(kp));
    if (p == 0) {
      float g = 1.f / (1.f + expf(-(YL[t][96] + b_gate[0])));
      sg[tok] = g;
      gsh[t] = g;
    }
  }
  __syncthreads();
  // gvT = (values + b_val) * gate; waves 0..7 own d cols < 256
  if (w < 8) {
#pragma unroll
    for (int nt = 0; nt < 2; ++nt) {
      int d = w * 32 + nt * 16 + ml;
      float bv = b_val[d];
      int t0 = quad * 4;
      short4 o;
      o.x = f2bf((acc[nt][0] + bv) * gsh[t0 + 0]);
      o.y = f2bf((acc[nt][1] + bv) * gsh[t0 + 1]);
      o.z = f2bf((acc[nt][2] + bv) * gsh[t0 + 2]);
      o.w = f2bf((acc[nt][3] + bv) * gsh[t0 + 3]);
      *(short4*)&gvT[(bc32 * 256 + d) * 32 + half * 16 + t0] = o;
    }
  }
}

// ---------------- gemmCD: ctx-in-LDS + gemm1 (hs in LDS) + kernelCD --------
// 256 blocks x 1024 threads (16 waves -> 4 waves/SIMD). Wave w owns 16 cols.
union __align__(16) CDMem {
  short As[32][520];                           // A tile [xbf | ctx], K=512
  struct { short HS[32][280]; short SPL[64][40]; } h;
};
__global__ __launch_bounds__(1024, 4) void gemmCD(const short* __restrict__ xbf,
                                                  const float* __restrict__ x,
                                                  const float* __restrict__ ctxsum,
                                                  const short* __restrict__ W1,
                                                  const float* __restrict__ b_sk1,
                                                  const short* __restrict__ W2T,
                                                  const float* __restrict__ b_sk2,
                                                  const short* __restrict__ gvT,
                                                  short* __restrict__ SPbf,
                                                  short* __restrict__ UT) {
  __shared__ CDMem sm;
  __shared__ float stmp[4][256];
  int tid = threadIdx.x;
  int bc = blockIdx.x;
  int tok0 = bc * 32;
  int bI = bc >> 6, ch = bc & 63;
  int lane = tid & 63, w = tid >> 6;
  int ml = lane & 15, quad = lane >> 4, kq = quad * 8;
  // stage xbf half of A (cols 0..255): 1024 short8, one per thread
  {
    int row = tid >> 5, c8 = tid & 31;
    *(short8_t*)&sm.As[row][c8 * 8] =
        *(const short8_t*)&xbf[(tok0 + row) * 256 + c8 * 8];
  }
  // ctx half (cols 256..511): prefix is ONE load; 4 token-quarters
  {
    int d = tid & 255, qh = tid >> 8;
    float cp = ctxsum[(bI * 64 + ch) * 256 + d];  // exclusive chunk prefix
    float xv[8];
    int xb = (tok0 + qh * 8) * 256 + d;
#pragma unroll
    for (int i = 0; i < 8; ++i) xv[i] = x[xb + i * 256];
    float p = 0.f;
#pragma unroll
    for (int i = 0; i < 8; ++i) p += xv[i];
    stmp[qh][d] = p;
    __syncthreads();
    float run = cp;
    for (int j = 0; j < qh; ++j) run += stmp[j][d];
    int l0 = ch * 32 + qh * 8;
#pragma unroll
    for (int i = 0; i < 8; ++i) {
      run += xv[i];
      sm.As[qh * 8 + i][256 + d] = f2bf(run / (float)(l0 + i + 1));
    }
  }
  __syncthreads();
  // hs = gelu(A @ W1 + b_sk1); wave w owns n-cols [w*16, w*16+16)
  int n0w = w * 16;
  floatx4 acc[2] = {};
#pragma unroll
  for (int kt = 0; kt < 16; ++kt) {
    short8_t a0 = *(short8_t*)&sm.As[ml][kt * 32 + kq];
    short8_t a1 = *(short8_t*)&sm.As[16 + ml][kt * 32 + kq];
    short8_t b0 = *(const short8_t*)&W1[(n0w + ml) * 512 + kt * 32 + kq];
    acc[0] = __builtin_amdgcn_mfma_f32_16x16x32_bf16(a0, b0, acc[0], 0, 0, 0);
    acc[1] = __builtin_amdgcn_mfma_f32_16x16x32_bf16(a1, b0, acc[1], 0, 0, 0);
  }
  short hv[2][4];
  {
    float bv = b_sk1[n0w + ml];
#pragma unroll
    for (int mt = 0; mt < 2; ++mt)
#pragma unroll
      for (int r = 0; r < 4; ++r) {
        float v = acc[mt][r] + bv;
        float g = 0.5f * v * (1.f + erff(v * 0.70710678118654752f));
        hv[mt][r] = f2bf(g);
      }
  }
  __syncthreads();  // As dead; HS aliases it
#pragma unroll
  for (int mt = 0; mt < 2; ++mt)
#pragma unroll
    for (int r = 0; r < 4; ++r)
      sm.h.HS[mt * 16 + quad * 4 + r][n0w + ml] = hv[mt][r];
  __syncthreads();
  // Phase B (waves 0..3): SP = tanh(hs @ W2T + b_sk2)*pi -> SPL + SPbf
  if (w < 4) {
    int th = w & 1, ph = w >> 1;
    floatx4 pacc = {};
#pragma unroll
    for (int s = 0; s < 8; ++s) {
      short8_t a = *(short8_t*)&sm.h.HS[th * 16 + ml][s * 32 + kq];
      short8_t b0 = *(const short8_t*)&W2T[(ph * 16 + ml) * 256 + s * 32 + kq];
      pacc = __builtin_amdgcn_mfma_f32_16x16x32_bf16(a, b0, pacc, 0, 0, 0);
    }
    int p = ph * 16 + ml;
    float bs = b_sk2[p];
#pragma unroll
    for (int r = 0; r < 4; ++r) {
      int tl = th * 16 + quad * 4 + r;
      int tok = tok0 + tl;
      float sp = tanhf(pacc[r] + bs) * PI_F;
      short c = f2bf(cosf(sp)), s2 = f2bf(sinf(sp));
      sm.h.SPL[p][tl] = c;
      sm.h.SPL[32 + p][tl] = s2;
      SPbf[tok * 64 + p] = c;
      SPbf[tok * 64 + 32 + p] = s2;
    }
  }
  __syncthreads();
  // Phase C: U chunk sums; wave w owns d in [w*16, w*16+16)
  short8_t a[4];
#pragma unroll
  for (int mt = 0; mt < 4; ++mt) a[mt] = *(short8_t*)&sm.h.SPL[mt * 16 + ml][kq];
  floatx4 acc3[4] = {};
  {
    int d = w * 16 + ml;
    short8_t b = *(const short8_t*)&gvT[(bc * 256 + d) * 32 + kq];
#pragma unroll
    for (int mt = 0; mt < 4; ++mt)
      acc3[mt] = __builtin_amdgcn_mfma_f32_16x16x32_bf16(a[mt], b, acc3[mt], 0, 0, 0);
  }
#pragma unroll
  for (int mt = 0; mt < 4; ++mt) {
    int d = w * 16 + ml;
    short4 o;
    o.x = f2bf(acc3[mt][0]);
    o.y = f2bf(acc3[mt][1]);
    o.z = f2bf(acc3[mt][2]);
    o.w = f2bf(acc3[mt][3]);
    *(short4*)&UT[(bc * 256 + d) * 64 + mt * 16 + quad * 4] = o;
  }
}

// ---------------- scanE: m1/sg token scans + UT chunk prefix (merged) ------
// Blocks 0..259: token scans (independent of E). Blocks 260..1283: kernelE
// 4-lane-split chunk prefix on UT. The two phases' latencies hide each other.
__global__ void scanE(float* __restrict__ m1cT, float* __restrict__ m1sT,
                      float* __restrict__ sg, short* __restrict__ UT) {
  int blk = blockIdx.x;
  int tid = threadIdx.x;
  if (blk >= 260) {
    int t = (blk - 260) * 256 + tid;  // 262144 threads
    int pi = t >> 2, j = t & 3;
    int q = pi & 63;
    int d = (pi >> 6) & 255;
    int b = pi >> 14;
    const int cs = 256 * 64;
    int base = ((b * NC) * 256 + d) * 64 + q + j * 16 * cs;
    short v[16];
#pragma unroll
    for (int c = 0; c < 16; ++c) v[c] = UT[base + c * cs];
    float tot = 0.f;
#pragma unroll
    for (int c = 0; c < 16; ++c) tot += bf2f(v[c]);
    int lane = tid & 63;
    int gb = lane & ~3;
    float t0 = __shfl(tot, gb + 0, 64);
    float t1 = __shfl(tot, gb + 1, 64);
    float t2 = __shfl(tot, gb + 2, 64);
    float run = (j > 0 ? t0 : 0.f) + (j > 1 ? t1 : 0.f) + (j > 2 ? t2 : 0.f);
#pragma unroll
    for (int c = 0; c < 16; ++c) {
      UT[base + c * cs] = f2bf(run);
      run += bf2f(v[c]);
    }
    return;
  }
  __shared__ float wsum[4];
  int lane = tid & 63, w = tid >> 6;
  float* arr;
  int base;
  if (blk < 256) {
    arr = (blk < 128) ? m1cT : m1sT;
    base = (blk & 127) * L_;
  } else {
    arr = sg;
    base = (blk - 256) * L_;
  }
  int sbase = base + w * 512;
  float v[8];
#pragma unroll
  for (int i = 0; i < 8; ++i) v[i] = arr[sbase + i * 64 + lane];
  float carry = 0.f;
#pragma unroll
  for (int i = 0; i < 8; ++i) {
    float vv = v[i];
#pragma unroll
    for (int off = 1; off < 64; off <<= 1) {
      float n = __shfl_up(vv, off, 64);
      if (lane >= off) vv += n;
    }
    vv += carry;
    v[i] = vv;
    carry = __shfl(vv, 63, 64);
  }
  if (lane == 0) wsum[w] = carry;
  __syncthreads();
  float off = 0.f;
  for (int ww = 0; ww < w; ++ww) off += wsum[ww];
#pragma unroll
  for (int i = 0; i < 8; ++i) arr[sbase + i * 64 + lane] = v[i] + off;
}

// ---------------- fgOut: retrieval + pos_out + LN + gemm2 -> out -----------
// 256 blocks x 1024 threads (16 waves -> 4 waves/SIMD); wave w owns 16 cols.
struct __align__(16) FGMem {
  short SL[32][40];
  short PR[32][40];
  float CMB[32][260];
  short CBN[32][280];
  float LG[256], LB[256];
  float scl[32], mu_s[32], rs_s[32];
};
__global__ __launch_bounds__(1024, 4) void fgOut(const short* __restrict__ UT,
                                                 const short* __restrict__ SPbf,
                                                 const short* __restrict__ K2bf,
                                                 const short* __restrict__ gvT,
                                                 const float* __restrict__ sgc,
                                                 const float* __restrict__ m1cT,
                                                 const float* __restrict__ m1sT,
                                                 const float* __restrict__ qc,
                                                 const float* __restrict__ qs,
                                                 const short* __restrict__ W1OT,
                                                 const float* __restrict__ b_mem1o,
                                                 const float* __restrict__ ln_g,
                                                 const float* __restrict__ ln_b,
                                                 const short* __restrict__ WO,
                                                 const float* __restrict__ b_out,
                                                 const float* __restrict__ x,
                                                 float* __restrict__ out) {
  __shared__ FGMem sm;
  int tid5 = threadIdx.x;
  int bc = blockIdx.x;
  int lbase = bc * CL;
  int bb = bc >> 6, lloc = (bc & 63) * 32;
  int lane = tid5 & 63, w = tid5 >> 6;
  int ml = lane & 15, quad = lane >> 4, kq = quad * 8;
  int d0 = w * 16;
  if (tid5 < 32) sm.scl[tid5] = rsqrtf(fmaxf(sgc[lbase + tid5], 1.f)) * INV_SQRT_P;
  if (tid5 >= 256 && tid5 < 512) {
    int d = tid5 - 256;
    sm.LG[d] = ln_g[d];
    sm.LB[d] = ln_b[d];
  }
  short8_t ka0 = *(const short8_t*)&K2bf[(lbase + ml) * 64 + kq];
  short8_t ka1 = *(const short8_t*)&K2bf[(lbase + 16 + ml) * 64 + kq];
  short8_t kb0 = *(const short8_t*)&K2bf[(lbase + ml) * 64 + 32 + kq];
  short8_t kb1 = *(const short8_t*)&K2bf[(lbase + 16 + ml) * 64 + 32 + kq];
  if (w == 0) {
    // S = K2 @ SP^T, mask, write SL
    floatx4 sacc[2][2] = {};
#pragma unroll
    for (int ks2 = 0; ks2 < 2; ++ks2) {
      short8_t a0 = (ks2 == 0) ? ka0 : kb0;
      short8_t a1 = (ks2 == 0) ? ka1 : kb1;
      short8_t b0 = *(const short8_t*)&SPbf[(lbase + ml) * 64 + ks2 * 32 + kq];
      short8_t b1 = *(const short8_t*)&SPbf[(lbase + 16 + ml) * 64 + ks2 * 32 + kq];
      sacc[0][0] = __builtin_amdgcn_mfma_f32_16x16x32_bf16(a0, b0, sacc[0][0], 0, 0, 0);
      sacc[0][1] = __builtin_amdgcn_mfma_f32_16x16x32_bf16(a0, b1, sacc[0][1], 0, 0, 0);
      sacc[1][0] = __builtin_amdgcn_mfma_f32_16x16x32_bf16(a1, b0, sacc[1][0], 0, 0, 0);
      sacc[1][1] = __builtin_amdgcn_mfma_f32_16x16x32_bf16(a1, b1, sacc[1][1], 0, 0, 0);
    }
#pragma unroll
    for (int mt = 0; mt < 2; ++mt)
#pragma unroll
      for (int nt = 0; nt < 2; ++nt)
#pragma unroll
        for (int r = 0; r < 4; ++r) {
          int trow = mt * 16 + quad * 4 + r;
          int scol = nt * 16 + ml;
          float v = (scol <= trow) ? sacc[mt][nt][r] : 0.f;
          sm.SL[trow][scol] = f2bf(v);
        }
  } else {
    // PR prep: 1024 items over 960 threads (waves 1-15)
    int t7 = tid5 - 64;
    for (int i = t7; i < 1024; i += 960) {
      int pp = i >> 5, t = i & 31;
      int gT = (bb * 32 + pp) * L_ + lloc + t;
      int g = (lbase + t) * 32 + pp;
      sm.PR[t][pp] = f2bf((m1cT[gT] * qc[g] + m1sT[gT] * qs[g]) * INV_SQRT_P);
    }
  }
  __syncthreads();
  // Part 1: K2 @ Uprev (both k-halves); wave w owns d [w*16, w*16+16)
  floatx4 acc[2] = {};
  {
    short8_t b0 = *(const short8_t*)&UT[(bc * 256 + d0 + ml) * 64 + kq];
    short8_t b1 = *(const short8_t*)&UT[(bc * 256 + d0 + ml) * 64 + 32 + kq];
    acc[0] = __builtin_amdgcn_mfma_f32_16x16x32_bf16(ka0, b0, acc[0], 0, 0, 0);
    acc[1] = __builtin_amdgcn_mfma_f32_16x16x32_bf16(ka1, b0, acc[1], 0, 0, 0);
    acc[0] = __builtin_amdgcn_mfma_f32_16x16x32_bf16(kb0, b1, acc[0], 0, 0, 0);
    acc[1] = __builtin_amdgcn_mfma_f32_16x16x32_bf16(kb1, b1, acc[1], 0, 0, 0);
  }
  // Part 2: S @ gv
  {
    short8_t a0 = *(short8_t*)&sm.SL[ml][kq];
    short8_t a1 = *(short8_t*)&sm.SL[16 + ml][kq];
    short8_t b = *(const short8_t*)&gvT[(bc * 256 + d0 + ml) * 32 + kq];
    acc[0] = __builtin_amdgcn_mfma_f32_16x16x32_bf16(a0, b, acc[0], 0, 0, 0);
    acc[1] = __builtin_amdgcn_mfma_f32_16x16x32_bf16(a1, b, acc[1], 0, 0, 0);
  }
  // pos_out MFMA
  floatx4 macc[2] = {};
  {
    short8_t a0 = *(short8_t*)&sm.PR[ml][kq];
    short8_t a1 = *(short8_t*)&sm.PR[16 + ml][kq];
    short8_t b = *(const short8_t*)&W1OT[(d0 + ml) * 32 + kq];
    macc[0] = __builtin_amdgcn_mfma_f32_16x16x32_bf16(a0, b, macc[0], 0, 0, 0);
    macc[1] = __builtin_amdgcn_mfma_f32_16x16x32_bf16(a1, b, macc[1], 0, 0, 0);
  }
  {
    int d = d0 + ml;
    float bm = b_mem1o[d];
#pragma unroll
    for (int mt = 0; mt < 2; ++mt)
#pragma unroll
      for (int r = 0; r < 4; ++r) {
        int t = mt * 16 + quad * 4 + r;
        sm.CMB[t][d] = acc[mt][r] * sm.scl[t] + macc[mt][r] + bm;
      }
  }
  __syncthreads();
  // LN stats: 32 threads per token, 8 elements each
  {
    int t = tid5 >> 5, g = tid5 & 31;
    float s = 0.f, s2 = 0.f;
#pragma unroll
    for (int j = 0; j < 8; ++j) {
      float v = sm.CMB[t][g + j * 32];
      s += v;
      s2 += v * v;
    }
#pragma unroll
    for (int m = 1; m < 32; m <<= 1) {
      s += __shfl_xor(s, m, 64);
      s2 += __shfl_xor(s2, m, 64);
    }
    if (g == 0) {
      float mu = s / (float)D_;
      float var = s2 / (float)D_ - mu * mu;
      sm.mu_s[t] = mu;
      sm.rs_s[t] = rsqrtf(var + 1e-5f);
    }
  }
  __syncthreads();
  // normalize -> CBN (bf16) in LDS
#pragma unroll
  for (int it = 0; it < 8; ++it) {
    int i = it * 1024 + tid5;
    int t = i >> 8, d = i & 255;
    sm.CBN[t][d] = f2bf((sm.CMB[t][d] - sm.mu_s[t]) * sm.rs_s[t] * sm.LG[d] + sm.LB[d]);
  }
  __syncthreads();
  // gemm2: out = x + CBN @ WO + b_out; wave w owns n-cols [w*16, +16)
  floatx4 acc2[2] = {};
#pragma unroll
  for (int kt = 0; kt < 8; ++kt) {
    short8_t a0 = *(short8_t*)&sm.CBN[ml][kt * 32 + kq];
    short8_t a1 = *(short8_t*)&sm.CBN[16 + ml][kt * 32 + kq];
    short8_t b = *(const short8_t*)&WO[(d0 + ml) * 256 + kt * 32 + kq];
    acc2[0] = __builtin_amdgcn_mfma_f32_16x16x32_bf16(a0, b, acc2[0], 0, 0, 0);
    acc2[1] = __builtin_amdgcn_mfma_f32_16x16x32_bf16(a1, b, acc2[1], 0, 0, 0);
  }
  {
    int n = d0 + ml;
    float bv = b_out[n];
#pragma unroll
    for (int mt = 0; mt < 2; ++mt)
#pragma unroll
      for (int r = 0; r < 4; ++r) {
        int tok = lbase + mt * 16 + quad * 4 + r;
        out[tok * 256 + n] = x[tok * 256 + n] + acc2[mt][r] + bv;
      }
  }
}

extern "C" void kernel_launch(void* const* d_in, const int* in_sizes, int n_in,
                              void* d_out, int out_size, void* d_ws, size_t ws_size,
                              hipStream_t stream) {
  const float* x = (const float*)d_in[0];
  const float* pos = (const float*)d_in[1];
  const float* w_mem1v = (const float*)d_in[2];
  const float* b_mem1v = (const float*)d_in[3];
  const float* w_mem1o = (const float*)d_in[4];
  const float* b_mem1o = (const float*)d_in[5];
  const float* w_off = (const float*)d_in[6];
  const float* b_off = (const float*)d_in[7];
  const float* w_key = (const float*)d_in[8];
  const float* b_key = (const float*)d_in[9];
  const float* w_val = (const float*)d_in[10];
  const float* b_val = (const float*)d_in[11];
  const float* w_sk1 = (const float*)d_in[12];
  const float* b_sk1 = (const float*)d_in[13];
  const float* w_sk2 = (const float*)d_in[14];
  const float* b_sk2 = (const float*)d_in[15];
  const float* w_gate = (const float*)d_in[16];
  const float* b_gate = (const float*)d_in[17];
  const float* ln_g = (const float*)d_in[18];
  const float* ln_b = (const float*)d_in[19];
  const float* w_out = (const float*)d_in[20];
  const float* b_out = (const float*)d_in[21];
  float* out = (float*)d_out;
  float* ws = (float*)d_ws;

  const int BLP = B_ * L_ * P_;  // 262144
  const int BLD = B_ * L_ * D_;  // 2097152
  float* m1cT = ws;
  float* m1sT = m1cT + BLP;
  float* qc = m1sT + BLP;
  float* qs = qc + BLP;
  float* sg = qs + BLP;
  float* poff = sg + B_ * L_;
  float* ctxsum = poff + L_ * P_;              // B*64*256 = 65536 floats
  short* UT = (short*)(ctxsum + B_ * 64 * 256);
  short* xbf = UT + (size_t)B_ * NC * 256 * 64;
  short* ctxbf = xbf + BLD;           // unused (layout stability)
  short* hs = ctxbf + BLD;            // unused (layout stability)
  short* gvT = hs + BLD;
  short* K2bf = gvT + BLD;            // B*L*64
  short* SPbf = K2bf + B_ * L_ * 64;  // B*L*64
  short* WA = SPbf + B_ * L_ * 64;
  short* W1 = WA + 384 * 256;
  short* WO = W1 + 256 * 512;
  short* W2T = WO + 256 * 256;
  short* W1OT = W2T + 32 * 256;

  wprep<<<1728, 256, 0, stream>>>(x, pos, w_val, w_mem1v, w_off, b_off, w_key, w_gate,
                                  w_sk1, w_out, w_sk2, w_mem1o, WA, W1, WO, W2T, W1OT,
                                  xbf, poff, ctxsum);
  gemmA3<<<516, 768, 0, stream>>>(xbf, WA, pos, poff, b_mem1v, b_key, b_gate, b_val,
                                  m1cT, m1sT, qc, qs, K2bf, gvT, sg, ctxsum);
  gemmCD<<<256, 1024, 0, stream>>>(xbf, x, ctxsum, W1, b_sk1, W2T, b_sk2, gvT, SPbf, UT);
  scanE<<<1284, 256, 0, stream>>>(m1cT, m1sT, sg, UT);
  fgOut<<<256, 1024, 0, stream>>>(UT, SPbf, K2bf, gvT, sg, m1cT, m1sT, qc, qs,
                                  W1OT, b_mem1o, ln_g, ln_b, WO, b_out, x, out);
}

// Round 9
// 159.670 us; speedup vs baseline: 2.5875x; 1.0192x over previous
//
#include <hip/hip_runtime.h>
#include <hip/hip_bf16.h>

constexpr int B_ = 4;
constexpr int L_ = 2048;
constexpr int D_ = 256;
constexpr int P_ = 32;
constexpr int CL = 32;   // chunk length for KV scan
constexpr int NC = L_ / CL;  // 64 chunks

#define PI_F 3.14159265358979323846f
#define INV_SQRT_P 0.17677669529663687f  // 1/sqrt(32)

typedef __attribute__((ext_vector_type(8))) short short8_t;
typedef __attribute__((ext_vector_type(4))) float floatx4;

static __device__ inline short f2bf(float f) {
  unsigned int u;
  __builtin_memcpy(&u, &f, 4);
  unsigned int r = (u + 0x7fffu + ((u >> 16) & 1u)) >> 16;
  return (short)r;
}
static __device__ inline float bf2f(short s) {
  unsigned int u = ((unsigned int)(unsigned short)s) << 16;
  float f;
  __builtin_memcpy(&f, &u, 4);
  return f;
}

// ---------------- wprep: weights + single-pass x->(xbf, ctxsum) + poff -----
__global__ void wprep(const float* __restrict__ x, const float* __restrict__ pos,
                      const float* __restrict__ w_val, const float* __restrict__ w_mem1v,
                      const float* __restrict__ w_off, const float* __restrict__ b_off,
                      const float* __restrict__ w_key, const float* __restrict__ w_gate,
                      const float* __restrict__ w_sk1, const float* __restrict__ w_out,
                      const float* __restrict__ w_sk2, const float* __restrict__ w_mem1o,
                      short* __restrict__ WA, short* __restrict__ W1,
                      short* __restrict__ WO, short* __restrict__ W2T,
                      short* __restrict__ W1OT,
                      short* __restrict__ xbf, float* __restrict__ poff,
                      float* __restrict__ ctxsum) {
  __shared__ float2 psum[2][128];
  int blk = blockIdx.x, tid = threadIdx.x;
  if (blk < 384) {
    int idx = blk * 256 + tid;
    int n = idx >> 8, k = idx & 255;
    float v;
    if (n < 256) v = w_val[k * 256 + n];
    else if (n < 288) v = w_mem1v[k * 32 + (n - 256)];
    else if (n < 320) v = w_off[k * 32 + (n - 288)];
    else if (n < 352) v = w_key[k * 32 + (n - 320)];
    else if (n == 352) v = w_gate[k];
    else v = 0.f;
    WA[idx] = f2bf(v);
  } else if (blk < 896) {
    int idx = (blk - 384) * 256 + tid;
    int n = idx >> 9, k = idx & 511;
    W1[idx] = f2bf(w_sk1[k * 256 + n]);
  } else if (blk < 1152) {
    int idx = (blk - 896) * 256 + tid;
    int n = idx >> 8, k = idx & 255;
    WO[idx] = f2bf(w_out[k * 256 + n]);
  } else if (blk < 1184) {
    int idx = (blk - 1152) * 256 + tid;  // p*256 + k
    int p = idx >> 8, k = idx & 255;
    W2T[idx] = f2bf(w_sk2[k * 32 + p]);
  } else if (blk < 1216) {
    int idx = (blk - 1184) * 256 + tid;  // d*32 + p
    int d = idx >> 5, p = idx & 31;
    W1OT[idx] = f2bf(w_mem1o[p * 256 + d]);
  } else if (blk < 1472) {
    int idx = (blk - 1216) * 256 + tid;
    int l = idx >> 5, p = idx & 31;
    float a = b_off[p];
#pragma unroll 8
    for (int j = 0; j < 32; ++j) a += pos[l * 32 + j] * w_off[(256 + j) * 32 + p];
    poff[idx] = a;
  } else {
    // single x pass: cast to xbf AND produce per-chunk d-sums (ctxsum)
    int c2 = blk - 1472;                 // 0..255 = (b, chunk)
    int b = c2 >> 6, ch = c2 & 63;
    int d2 = (tid & 127) * 2, h = tid >> 7;
    int tokb = b * L_ + ch * 32 + h * 16;
    float2 xv[16];
#pragma unroll
    for (int i = 0; i < 16; ++i)
      xv[i] = *(const float2*)&x[(tokb + i) * 256 + d2];
    float2 s = {0.f, 0.f};
#pragma unroll
    for (int i = 0; i < 16; ++i) { s.x += xv[i].x; s.y += xv[i].y; }
#pragma unroll
    for (int i = 0; i < 16; ++i) {
      short2 o;
      o.x = f2bf(xv[i].x);
      o.y = f2bf(xv[i].y);
      *(short2*)&xbf[(tokb + i) * 256 + d2] = o;
    }
    psum[h][tid & 127] = s;
    __syncthreads();
    if (h == 0) {
      float2 o = psum[1][tid & 127];
      float2 tot = {s.x + o.x, s.y + o.y};
      *(float2*)&ctxsum[c2 * 256 + d2] = tot;
    }
  }
}

// ---------------- gemmA3: fused gemm1 + A3 epilogue + ctx-prefix blocks ----
__global__ __launch_bounds__(768, 6) void gemmA3(const short* __restrict__ xbf,
                                                 const short* __restrict__ WA,
                                                 const float* __restrict__ pos,
                                                 const float* __restrict__ poff,
                                                 const float* __restrict__ b_mem1v,
                                                 const float* __restrict__ b_key,
                                                 const float* __restrict__ b_gate,
                                                 const float* __restrict__ b_val,
                                                 float* __restrict__ m1cT,
                                                 float* __restrict__ m1sT,
                                                 float* __restrict__ qc,
                                                 float* __restrict__ qs,
                                                 short* __restrict__ K2bf,
                                                 short* __restrict__ gvT,
                                                 float* __restrict__ sg,
                                                 float* __restrict__ ctxsum) {
  __shared__ float YL[16][132];  // cols 256..383 of Y, fp32
  __shared__ float gsh[16];
  int tid = threadIdx.x;
  int bc = blockIdx.x;
  if (bc >= 512) {
    // ctx-prefix: batch-8 loads, exclusive prefix over 64 chunks per (b,d)
    if (tid < 256) {
      int b = bc - 512;
      int base = b * 64 * 256 + tid;
      float run = 0.f;
      for (int c0 = 0; c0 < 64; c0 += 8) {
        float v[8];
#pragma unroll
        for (int j = 0; j < 8; ++j) v[j] = ctxsum[base + (c0 + j) * 256];
#pragma unroll
        for (int j = 0; j < 8; ++j) {
          ctxsum[base + (c0 + j) * 256] = run;
          run += v[j];
        }
      }
    }
    return;
  }
  int lane = tid & 63, w = tid >> 6;
  int ml = lane & 15, quad = lane >> 4, kq = quad * 8;
  int bc32 = bc >> 1, half = bc & 1;
  int tok0 = bc * 16;
  // prefetch epilogue operands (consumed after the barrier; hides latency
  // under the MFMA loop)
  float posv = 0.f, poffv = 0.f;
  if (tid < 512) {
    int t = tid >> 5, p = tid & 31;
    int l = (tok0 + t) & (L_ - 1);
    posv = pos[l * 32 + p];
    poffv = poff[l * 32 + p];
  }
  floatx4 acc[2] = {};
  const short* A0p = &xbf[(tok0 + ml) * 256 + kq];
  const short* Bp = &WA[(w * 32 + ml) * 256 + kq];
#pragma unroll
  for (int ks = 0; ks < 8; ++ks) {
    short8_t a0 = *(const short8_t*)(A0p + ks * 32);
#pragma unroll
    for (int nt = 0; nt < 2; ++nt) {
      short8_t b = *(const short8_t*)(Bp + nt * 16 * 256 + ks * 32);
      acc[nt] = __builtin_amdgcn_mfma_f32_16x16x32_bf16(a0, b, acc[nt], 0, 0, 0);
    }
  }
  // waves 8..11 stage cols 256..383 into LDS (fp32)
  if (w >= 8) {
#pragma unroll
    for (int nt = 0; nt < 2; ++nt) {
      int col = (w - 8) * 32 + nt * 16 + ml;
#pragma unroll
      for (int r = 0; r < 4; ++r)
        YL[quad * 4 + r][col] = acc[nt][r];
    }
  }
  __syncthreads();
  // A3 elementwise phase: 16 tok x 32 p = 512 items on threads 0..511
  if (tid < 512) {
    int t = tid >> 5, p = tid & 31;
    int tok = tok0 + t, l = tok & (L_ - 1);
    int b = tok >> 11;
    float v1 = YL[t][p] + b_mem1v[p];
    float pc = cosf(posv), ps = sinf(posv);
    int idxT = (b * 32 + p) * L_ + l;
    m1cT[idxT] = pc * v1;
    m1sT[idxT] = ps * v1;
    float off = tanhf(YL[t][32 + p] + poffv) * PI_F;
    float oc = cosf(off), os = sinf(off);
    int gidx = tok * 32 + p;
    qc[gidx] = pc * oc - ps * os;
    qs[gidx] = ps * oc + pc * os;
    float kp = tanhf(YL[t][64 + p] + b_key[p]) * PI_F;
    K2bf[tok * 64 + p] = f2bf(cosf(kp));
    K2bf[tok * 64 + 32 + p] = f2bf(sinf(kp));
    if (p == 0) {
      float g = 1.f / (1.f + expf(-(YL[t][96] + b_gate[0])));
      sg[tok] = g;
      gsh[t] = g;
    }
  }
  __syncthreads();
  // gvT = (values + b_val) * gate; waves 0..7 own d cols < 256
  if (w < 8) {
#pragma unroll
    for (int nt = 0; nt < 2; ++nt) {
      int d = w * 32 + nt * 16 + ml;
      float bv = b_val[d];
      int t0 = quad * 4;
      short4 o;
      o.x = f2bf((acc[nt][0] + bv) * gsh[t0 + 0]);
      o.y = f2bf((acc[nt][1] + bv) * gsh[t0 + 1]);
      o.z = f2bf((acc[nt][2] + bv) * gsh[t0 + 2]);
      o.w = f2bf((acc[nt][3] + bv) * gsh[t0 + 3]);
      *(short4*)&gvT[(bc32 * 256 + d) * 32 + half * 16 + t0] = o;
    }
  }
}

// ---------------- gemmCD: ctx-in-LDS + gemm1 (hs in LDS) + kernelCD --------
union __align__(16) CDMem {
  short As[32][520];                           // A tile [xbf | ctx], K=512
  struct { short HS[32][280]; short SPL[64][40]; } h;
};
__global__ __launch_bounds__(1024, 4) void gemmCD(const short* __restrict__ xbf,
                                                  const float* __restrict__ x,
                                                  const float* __restrict__ ctxsum,
                                                  const short* __restrict__ W1,
                                                  const float* __restrict__ b_sk1,
                                                  const short* __restrict__ W2T,
                                                  const float* __restrict__ b_sk2,
                                                  const short* __restrict__ gvT,
                                                  short* __restrict__ SPbf,
                                                  short* __restrict__ UT) {
  __shared__ CDMem sm;
  __shared__ float stmp[4][256];
  int tid = threadIdx.x;
  int bc = blockIdx.x;
  int tok0 = bc * 32;
  int bI = bc >> 6, ch = bc & 63;
  int lane = tid & 63, w = tid >> 6;
  int ml = lane & 15, quad = lane >> 4, kq = quad * 8;
  // prefetch phase-C gvT B-frag (consumed after 4 barriers; hides HBM latency)
  short8_t bgv = *(const short8_t*)&gvT[(bc * 256 + w * 16 + ml) * 32 + kq];
  // stage xbf half of A (cols 0..255): 1024 short8, one per thread
  {
    int row = tid >> 5, c8 = tid & 31;
    *(short8_t*)&sm.As[row][c8 * 8] =
        *(const short8_t*)&xbf[(tok0 + row) * 256 + c8 * 8];
  }
  // ctx half (cols 256..511): prefix is ONE load; 4 token-quarters
  {
    int d = tid & 255, qh = tid >> 8;
    float cp = ctxsum[(bI * 64 + ch) * 256 + d];  // exclusive chunk prefix
    float xv[8];
    int xb = (tok0 + qh * 8) * 256 + d;
#pragma unroll
    for (int i = 0; i < 8; ++i) xv[i] = x[xb + i * 256];
    float p = 0.f;
#pragma unroll
    for (int i = 0; i < 8; ++i) p += xv[i];
    stmp[qh][d] = p;
    __syncthreads();
    float run = cp;
    for (int j = 0; j < qh; ++j) run += stmp[j][d];
    int l0 = ch * 32 + qh * 8;
#pragma unroll
    for (int i = 0; i < 8; ++i) {
      run += xv[i];
      sm.As[qh * 8 + i][256 + d] = f2bf(run / (float)(l0 + i + 1));
    }
  }
  __syncthreads();
  // hs = gelu(A @ W1 + b_sk1); wave w owns n-cols [w*16, w*16+16)
  int n0w = w * 16;
  floatx4 acc[2] = {};
#pragma unroll
  for (int kt = 0; kt < 16; ++kt) {
    short8_t a0 = *(short8_t*)&sm.As[ml][kt * 32 + kq];
    short8_t a1 = *(short8_t*)&sm.As[16 + ml][kt * 32 + kq];
    short8_t b0 = *(const short8_t*)&W1[(n0w + ml) * 512 + kt * 32 + kq];
    acc[0] = __builtin_amdgcn_mfma_f32_16x16x32_bf16(a0, b0, acc[0], 0, 0, 0);
    acc[1] = __builtin_amdgcn_mfma_f32_16x16x32_bf16(a1, b0, acc[1], 0, 0, 0);
  }
  short hv[2][4];
  {
    float bv = b_sk1[n0w + ml];
#pragma unroll
    for (int mt = 0; mt < 2; ++mt)
#pragma unroll
      for (int r = 0; r < 4; ++r) {
        float v = acc[mt][r] + bv;
        float g = 0.5f * v * (1.f + erff(v * 0.70710678118654752f));
        hv[mt][r] = f2bf(g);
      }
  }
  __syncthreads();  // As dead; HS aliases it
#pragma unroll
  for (int mt = 0; mt < 2; ++mt)
#pragma unroll
    for (int r = 0; r < 4; ++r)
      sm.h.HS[mt * 16 + quad * 4 + r][n0w + ml] = hv[mt][r];
  __syncthreads();
  // Phase B (waves 0..3): SP = tanh(hs @ W2T + b_sk2)*pi -> SPL + SPbf
  if (w < 4) {
    int th = w & 1, ph = w >> 1;
    floatx4 pacc = {};
#pragma unroll
    for (int s = 0; s < 8; ++s) {
      short8_t a = *(short8_t*)&sm.h.HS[th * 16 + ml][s * 32 + kq];
      short8_t b0 = *(const short8_t*)&W2T[(ph * 16 + ml) * 256 + s * 32 + kq];
      pacc = __builtin_amdgcn_mfma_f32_16x16x32_bf16(a, b0, pacc, 0, 0, 0);
    }
    int p = ph * 16 + ml;
    float bs = b_sk2[p];
#pragma unroll
    for (int r = 0; r < 4; ++r) {
      int tl = th * 16 + quad * 4 + r;
      int tok = tok0 + tl;
      float sp = tanhf(pacc[r] + bs) * PI_F;
      short c = f2bf(cosf(sp)), s2 = f2bf(sinf(sp));
      sm.h.SPL[p][tl] = c;
      sm.h.SPL[32 + p][tl] = s2;
      SPbf[tok * 64 + p] = c;
      SPbf[tok * 64 + 32 + p] = s2;
    }
  }
  __syncthreads();
  // Phase C: U chunk sums; wave w owns d in [w*16, w*16+16)
  short8_t a[4];
#pragma unroll
  for (int mt = 0; mt < 4; ++mt) a[mt] = *(short8_t*)&sm.h.SPL[mt * 16 + ml][kq];
  floatx4 acc3[4] = {};
#pragma unroll
  for (int mt = 0; mt < 4; ++mt)
    acc3[mt] = __builtin_amdgcn_mfma_f32_16x16x32_bf16(a[mt], bgv, acc3[mt], 0, 0, 0);
#pragma unroll
  for (int mt = 0; mt < 4; ++mt) {
    int d = w * 16 + ml;
    short4 o;
    o.x = f2bf(acc3[mt][0]);
    o.y = f2bf(acc3[mt][1]);
    o.z = f2bf(acc3[mt][2]);
    o.w = f2bf(acc3[mt][3]);
    *(short4*)&UT[(bc * 256 + d) * 64 + mt * 16 + quad * 4] = o;
  }
}

// ---------------- scanE: m1/sg token scans + UT chunk prefix (merged) ------
// Blocks 0..259: token scans. Blocks 260..1283: coalesced E — wave w owns
// chunk-group [w*16,w*16+16), lanes = 64 consecutive q -> 128B transactions;
// cross-wave stitch via LDS.
__global__ void scanE(float* __restrict__ m1cT, float* __restrict__ m1sT,
                      float* __restrict__ sg, short* __restrict__ UT) {
  __shared__ float wsum[4];
  __shared__ float stot[4][64];
  int blk = blockIdx.x;
  int tid = threadIdx.x;
  if (blk >= 260) {
    int eb = blk - 260;               // 0..1023
    int w = tid >> 6, lane = tid & 63;
    int pi = eb * 64 + lane;          // 64 consecutive pi per block
    int q = pi & 63;
    int d = (pi >> 6) & 255;
    int b = pi >> 14;
    const int cs = 256 * 64;
    int base = ((b * NC) * 256 + d) * 64 + q;
    short v[16];
#pragma unroll
    for (int c = 0; c < 16; ++c) v[c] = UT[base + (w * 16 + c) * cs];
    float tot = 0.f;
#pragma unroll
    for (int c = 0; c < 16; ++c) tot += bf2f(v[c]);
    stot[w][lane] = tot;
    __syncthreads();
    float run = 0.f;
    for (int ww = 0; ww < w; ++ww) run += stot[ww][lane];
#pragma unroll
    for (int c = 0; c < 16; ++c) {
      UT[base + (w * 16 + c) * cs] = f2bf(run);
      run += bf2f(v[c]);
    }
    return;
  }
  int lane = tid & 63, w = tid >> 6;
  float* arr;
  int base;
  if (blk < 256) {
    arr = (blk < 128) ? m1cT : m1sT;
    base = (blk & 127) * L_;
  } else {
    arr = sg;
    base = (blk - 256) * L_;
  }
  int sbase = base + w * 512;
  float v[8];
#pragma unroll
  for (int i = 0; i < 8; ++i) v[i] = arr[sbase + i * 64 + lane];
  float carry = 0.f;
#pragma unroll
  for (int i = 0; i < 8; ++i) {
    float vv = v[i];
#pragma unroll
    for (int off = 1; off < 64; off <<= 1) {
      float n = __shfl_up(vv, off, 64);
      if (lane >= off) vv += n;
    }
    vv += carry;
    v[i] = vv;
    carry = __shfl(vv, 63, 64);
  }
  if (lane == 0) wsum[w] = carry;
  __syncthreads();
  float off = 0.f;
  for (int ww = 0; ww < w; ++ww) off += wsum[ww];
#pragma unroll
  for (int i = 0; i < 8; ++i) arr[sbase + i * 64 + lane] = v[i] + off;
}

// ---------------- fgOut: retrieval + pos_out + LN + gemm2 -> out -----------
// Prefetched UT/gvT/W1OT frags + x residual at entry; coalesced float4
// epilogue through LDS.
struct __align__(16) FGMem {
  short SL[32][40];
  short PR[32][40];
  float CMB[32][260];
  short CBN[32][280];
  float LG[256], LB[256];
  float scl[32], mu_s[32], rs_s[32];
};
__global__ __launch_bounds__(1024, 4) void fgOut(const short* __restrict__ UT,
                                                 const short* __restrict__ SPbf,
                                                 const short* __restrict__ K2bf,
                                                 const short* __restrict__ gvT,
                                                 const float* __restrict__ sgc,
                                                 const float* __restrict__ m1cT,
                                                 const float* __restrict__ m1sT,
                                                 const float* __restrict__ qc,
                                                 const float* __restrict__ qs,
                                                 const short* __restrict__ W1OT,
                                                 const float* __restrict__ b_mem1o,
                                                 const float* __restrict__ ln_g,
                                                 const float* __restrict__ ln_b,
                                                 const short* __restrict__ WO,
                                                 const float* __restrict__ b_out,
                                                 const float* __restrict__ x,
                                                 float* __restrict__ out) {
  __shared__ FGMem sm;
  int tid5 = threadIdx.x;
  int bc = blockIdx.x;
  int lbase = bc * CL;
  int bb = bc >> 6, lloc = (bc & 63) * 32;
  int lane = tid5 & 63, w = tid5 >> 6;
  int ml = lane & 15, quad = lane >> 4, kq = quad * 8;
  int d0 = w * 16;
  // ---- entry prefetches (consumed after barriers; hide HBM latency) ----
  short8_t ub0 = *(const short8_t*)&UT[(bc * 256 + d0 + ml) * 64 + kq];
  short8_t ub1 = *(const short8_t*)&UT[(bc * 256 + d0 + ml) * 64 + 32 + kq];
  short8_t gvb = *(const short8_t*)&gvT[(bc * 256 + d0 + ml) * 32 + kq];
  short8_t w1b = *(const short8_t*)&W1OT[(d0 + ml) * 32 + kq];
  const float4* x4 = (const float4*)&x[lbase * 256];
  float4 xp0 = x4[tid5];
  float4 xp1 = x4[tid5 + 1024];
  if (tid5 < 32) sm.scl[tid5] = rsqrtf(fmaxf(sgc[lbase + tid5], 1.f)) * INV_SQRT_P;
  if (tid5 >= 256 && tid5 < 512) {
    int d = tid5 - 256;
    sm.LG[d] = ln_g[d];
    sm.LB[d] = ln_b[d];
  }
  short8_t ka0 = *(const short8_t*)&K2bf[(lbase + ml) * 64 + kq];
  short8_t ka1 = *(const short8_t*)&K2bf[(lbase + 16 + ml) * 64 + kq];
  short8_t kb0 = *(const short8_t*)&K2bf[(lbase + ml) * 64 + 32 + kq];
  short8_t kb1 = *(const short8_t*)&K2bf[(lbase + 16 + ml) * 64 + 32 + kq];
  if (w == 0) {
    // S = K2 @ SP^T, mask, write SL
    floatx4 sacc[2][2] = {};
#pragma unroll
    for (int ks2 = 0; ks2 < 2; ++ks2) {
      short8_t a0 = (ks2 == 0) ? ka0 : kb0;
      short8_t a1 = (ks2 == 0) ? ka1 : kb1;
      short8_t b0 = *(const short8_t*)&SPbf[(lbase + ml) * 64 + ks2 * 32 + kq];
      short8_t b1 = *(const short8_t*)&SPbf[(lbase + 16 + ml) * 64 + ks2 * 32 + kq];
      sacc[0][0] = __builtin_amdgcn_mfma_f32_16x16x32_bf16(a0, b0, sacc[0][0], 0, 0, 0);
      sacc[0][1] = __builtin_amdgcn_mfma_f32_16x16x32_bf16(a0, b1, sacc[0][1], 0, 0, 0);
      sacc[1][0] = __builtin_amdgcn_mfma_f32_16x16x32_bf16(a1, b0, sacc[1][0], 0, 0, 0);
      sacc[1][1] = __builtin_amdgcn_mfma_f32_16x16x32_bf16(a1, b1, sacc[1][1], 0, 0, 0);
    }
#pragma unroll
    for (int mt = 0; mt < 2; ++mt)
#pragma unroll
      for (int nt = 0; nt < 2; ++nt)
#pragma unroll
        for (int r = 0; r < 4; ++r) {
          int trow = mt * 16 + quad * 4 + r;
          int scol = nt * 16 + ml;
          float v = (scol <= trow) ? sacc[mt][nt][r] : 0.f;
          sm.SL[trow][scol] = f2bf(v);
        }
  } else {
    // PR prep: 1024 items over 960 threads (waves 1-15)
    int t7 = tid5 - 64;
    for (int i = t7; i < 1024; i += 960) {
      int pp = i >> 5, t = i & 31;
      int gT = (bb * 32 + pp) * L_ + lloc + t;
      int g = (lbase + t) * 32 + pp;
      sm.PR[t][pp] = f2bf((m1cT[gT] * qc[g] + m1sT[gT] * qs[g]) * INV_SQRT_P);
    }
  }
  __syncthreads();
  // Part 1: K2 @ Uprev (both k-halves); B-frags were prefetched
  floatx4 acc[2] = {};
  acc[0] = __builtin_amdgcn_mfma_f32_16x16x32_bf16(ka0, ub0, acc[0], 0, 0, 0);
  acc[1] = __builtin_amdgcn_mfma_f32_16x16x32_bf16(ka1, ub0, acc[1], 0, 0, 0);
  acc[0] = __builtin_amdgcn_mfma_f32_16x16x32_bf16(kb0, ub1, acc[0], 0, 0, 0);
  acc[1] = __builtin_amdgcn_mfma_f32_16x16x32_bf16(kb1, ub1, acc[1], 0, 0, 0);
  // Part 2: S @ gv
  {
    short8_t a0 = *(short8_t*)&sm.SL[ml][kq];
    short8_t a1 = *(short8_t*)&sm.SL[16 + ml][kq];
    acc[0] = __builtin_amdgcn_mfma_f32_16x16x32_bf16(a0, gvb, acc[0], 0, 0, 0);
    acc[1] = __builtin_amdgcn_mfma_f32_16x16x32_bf16(a1, gvb, acc[1], 0, 0, 0);
  }
  // pos_out MFMA
  floatx4 macc[2] = {};
  {
    short8_t a0 = *(short8_t*)&sm.PR[ml][kq];
    short8_t a1 = *(short8_t*)&sm.PR[16 + ml][kq];
    macc[0] = __builtin_amdgcn_mfma_f32_16x16x32_bf16(a0, w1b, macc[0], 0, 0, 0);
    macc[1] = __builtin_amdgcn_mfma_f32_16x16x32_bf16(a1, w1b, macc[1], 0, 0, 0);
  }
  {
    int d = d0 + ml;
    float bm = b_mem1o[d];
#pragma unroll
    for (int mt = 0; mt < 2; ++mt)
#pragma unroll
      for (int r = 0; r < 4; ++r) {
        int t = mt * 16 + quad * 4 + r;
        sm.CMB[t][d] = acc[mt][r] * sm.scl[t] + macc[mt][r] + bm;
      }
  }
  __syncthreads();
  // LN stats: 32 threads per token, 8 elements each
  {
    int t = tid5 >> 5, g = tid5 & 31;
    float s = 0.f, s2 = 0.f;
#pragma unroll
    for (int j = 0; j < 8; ++j) {
      float v = sm.CMB[t][g + j * 32];
      s += v;
      s2 += v * v;
    }
#pragma unroll
    for (int m = 1; m < 32; m <<= 1) {
      s += __shfl_xor(s, m, 64);
      s2 += __shfl_xor(s2, m, 64);
    }
    if (g == 0) {
      float mu = s / (float)D_;
      float var = s2 / (float)D_ - mu * mu;
      sm.mu_s[t] = mu;
      sm.rs_s[t] = rsqrtf(var + 1e-5f);
    }
  }
  __syncthreads();
  // normalize -> CBN (bf16) in LDS
#pragma unroll
  for (int it = 0; it < 8; ++it) {
    int i = it * 1024 + tid5;
    int t = i >> 8, d = i & 255;
    sm.CBN[t][d] = f2bf((sm.CMB[t][d] - sm.mu_s[t]) * sm.rs_s[t] * sm.LG[d] + sm.LB[d]);
  }
  __syncthreads();
  // gemm2: CBN @ WO + b_out -> CMB (reuse; dead after CBN built)
  floatx4 acc2[2] = {};
#pragma unroll
  for (int kt = 0; kt < 8; ++kt) {
    short8_t a0 = *(short8_t*)&sm.CBN[ml][kt * 32 + kq];
    short8_t a1 = *(short8_t*)&sm.CBN[16 + ml][kt * 32 + kq];
    short8_t b = *(const short8_t*)&WO[(d0 + ml) * 256 + kt * 32 + kq];
    acc2[0] = __builtin_amdgcn_mfma_f32_16x16x32_bf16(a0, b, acc2[0], 0, 0, 0);
    acc2[1] = __builtin_amdgcn_mfma_f32_16x16x32_bf16(a1, b, acc2[1], 0, 0, 0);
  }
  {
    int n = d0 + ml;
    float bv = b_out[n];
#pragma unroll
    for (int mt = 0; mt < 2; ++mt)
#pragma unroll
      for (int r = 0; r < 4; ++r) {
        int t = mt * 16 + quad * 4 + r;
        sm.CMB[t][n] = acc2[mt][r] + bv;
      }
  }
  __syncthreads();
  // coalesced float4 epilogue: out = x + CMB
  {
    float4* o4 = (float4*)&out[lbase * 256];
#pragma unroll
    for (int k = 0; k < 2; ++k) {
      int idx4 = tid5 + k * 1024;
      int t = idx4 >> 6, dd = (idx4 & 63) * 4;
      float4 xp = (k == 0) ? xp0 : xp1;
      float4 o;
      o.x = xp.x + sm.CMB[t][dd + 0];
      o.y = xp.y + sm.CMB[t][dd + 1];
      o.z = xp.z + sm.CMB[t][dd + 2];
      o.w = xp.w + sm.CMB[t][dd + 3];
      o4[idx4] = o;
    }
  }
}

extern "C" void kernel_launch(void* const* d_in, const int* in_sizes, int n_in,
                              void* d_out, int out_size, void* d_ws, size_t ws_size,
                              hipStream_t stream) {
  const float* x = (const float*)d_in[0];
  const float* pos = (const float*)d_in[1];
  const float* w_mem1v = (const float*)d_in[2];
  const float* b_mem1v = (const float*)d_in[3];
  const float* w_mem1o = (const float*)d_in[4];
  const float* b_mem1o = (const float*)d_in[5];
  const float* w_off = (const float*)d_in[6];
  const float* b_off = (const float*)d_in[7];
  const float* w_key = (const float*)d_in[8];
  const float* b_key = (const float*)d_in[9];
  const float* w_val = (const float*)d_in[10];
  const float* b_val = (const float*)d_in[11];
  const float* w_sk1 = (const float*)d_in[12];
  const float* b_sk1 = (const float*)d_in[13];
  const float* w_sk2 = (const float*)d_in[14];
  const float* b_sk2 = (const float*)d_in[15];
  const float* w_gate = (const float*)d_in[16];
  const float* b_gate = (const float*)d_in[17];
  const float* ln_g = (const float*)d_in[18];
  const float* ln_b = (const float*)d_in[19];
  const float* w_out = (const float*)d_in[20];
  const float* b_out = (const float*)d_in[21];
  float* out = (float*)d_out;
  float* ws = (float*)d_ws;

  const int BLP = B_ * L_ * P_;  // 262144
  const int BLD = B_ * L_ * D_;  // 2097152
  float* m1cT = ws;
  float* m1sT = m1cT + BLP;
  float* qc = m1sT + BLP;
  float* qs = qc + BLP;
  float* sg = qs + BLP;
  float* poff = sg + B_ * L_;
  float* ctxsum = poff + L_ * P_;              // B*64*256 = 65536 floats
  short* UT = (short*)(ctxsum + B_ * 64 * 256);
  short* xbf = UT + (size_t)B_ * NC * 256 * 64;
  short* ctxbf = xbf + BLD;           // unused (layout stability)
  short* hs = ctxbf + BLD;            // unused (layout stability)
  short* gvT = hs + BLD;
  short* K2bf = gvT + BLD;            // B*L*64
  short* SPbf = K2bf + B_ * L_ * 64;  // B*L*64
  short* WA = SPbf + B_ * L_ * 64;
  short* W1 = WA + 384 * 256;
  short* WO = W1 + 256 * 512;
  short* W2T = WO + 256 * 256;
  short* W1OT = W2T + 32 * 256;

  wprep<<<1728, 256, 0, stream>>>(x, pos, w_val, w_mem1v, w_off, b_off, w_key, w_gate,
                                  w_sk1, w_out, w_sk2, w_mem1o, WA, W1, WO, W2T, W1OT,
                                  xbf, poff, ctxsum);
  gemmA3<<<516, 768, 0, stream>>>(xbf, WA, pos, poff, b_mem1v, b_key, b_gate, b_val,
                                  m1cT, m1sT, qc, qs, K2bf, gvT, sg, ctxsum);
  gemmCD<<<256, 1024, 0, stream>>>(xbf, x, ctxsum, W1, b_sk1, W2T, b_sk2, gvT, SPbf, UT);
  scanE<<<1284, 256, 0, stream>>>(m1cT, m1sT, sg, UT);
  fgOut<<<256, 1024, 0, stream>>>(UT, SPbf, K2bf, gvT, sg, m1cT, m1sT, qc, qs,
                                  W1OT, b_mem1o, ln_g, ln_b, WO, b_out, x, out);
}